// Round 8
// baseline (601.907 us; speedup 1.0000x reference)
//
#include <hip/hip_runtime.h>

#define NRES 384
#define CZ 128
#define NH 4
#define CH 32
#define NN (NRES * NRES)
#define NNCZ ((size_t)NN * CZ)

typedef unsigned short u16;
typedef __attribute__((ext_vector_type(4))) unsigned short us4;
typedef __attribute__((ext_vector_type(8))) unsigned short us8;
typedef __attribute__((ext_vector_type(8))) short s8;   // 8 bf16 = MFMA A/B frag
typedef __attribute__((ext_vector_type(4))) float f4;   // MFMA C/D frag

#define L2E 1.4426950408889634f

__device__ __forceinline__ float bf2f(u16 u) {
  return __uint_as_float(((unsigned)u) << 16);
}
__device__ __forceinline__ u16 f2bf(float f) {
  unsigned u = __float_as_uint(f);
  u += 0x7fffu + ((u >> 16) & 1u);  // RTNE
  return (u16)(u >> 16);
}

template<bool F32>
__device__ __forceinline__ float ld1(const void* p, size_t i) {
  if constexpr (F32) return ((const float*)p)[i];
  else return bf2f(((const u16*)p)[i]);
}

template<bool F32>
__device__ __forceinline__ void ld4v(const void* p, size_t i, float o[4]) {
  if constexpr (F32) {
    const float4 a = *(const float4*)((const float*)p + i);
    o[0] = a.x; o[1] = a.y; o[2] = a.z; o[3] = a.w;
  } else {
    const us4 v = *(const us4*)((const u16*)p + i);
    #pragma unroll
    for (int u = 0; u < 4; ++u) o[u] = bf2f(v[u]);
  }
}

template<bool F32>
__device__ __forceinline__ void ld8(const void* p, size_t i, float o[8]) {
  if constexpr (F32) {
    const float4 a = *(const float4*)((const float*)p + i);
    const float4 b = *(const float4*)((const float*)p + i + 4);
    o[0] = a.x; o[1] = a.y; o[2] = a.z; o[3] = a.w;
    o[4] = b.x; o[5] = b.y; o[6] = b.z; o[7] = b.w;
  } else {
    const us8 v = *(const us8*)((const u16*)p + i);
    #pragma unroll
    for (int u = 0; u < 8; ++u) o[u] = bf2f(v[u]);
  }
}

// ---------------------------------------------------------------------------
// Probe: decide input dtype from z's exponent-bit statistics.
// ---------------------------------------------------------------------------
__global__ void k_probe(const u16* __restrict__ z, int* __restrict__ flag) {
  int weird = 0;
  for (int i = threadIdx.x; i < 256; i += 64) {
    const int e = (z[i] >> 7) & 0xFF;
    if (e < 0x70 || e > 0x8F) weird++;
  }
  #pragma unroll
  for (int m = 1; m < 64; m <<= 1) weird += __shfl_xor(weird, m, 64);
  if (threadIdx.x == 0) *flag = (weird >= 16) ? 1 : 0;
}

// ---------------------------------------------------------------------------
// K1: LayerNorm + MFMA projections + tri_bias (transposed out).
// (unchanged)
// ---------------------------------------------------------------------------
template<bool F32>
__global__ __launch_bounds__(256, 2) void k_ln_proj(
    const void* __restrict__ z, const void* __restrict__ gma, const void* __restrict__ bta,
    const void* __restrict__ wbias, const void* __restrict__ wq, const void* __restrict__ wk,
    const void* __restrict__ wv, const void* __restrict__ wg, const void* __restrict__ bg,
    u16* __restrict__ qb, u16* __restrict__ kb, u16* __restrict__ vb, u16* __restrict__ gb,
    float* __restrict__ triT, const int* __restrict__ flag)
{
  if ((*flag != 0) != F32) return;
  __shared__ __align__(16) u16 znl[128 * 136];   // 34816 B
  __shared__ __align__(16) u16 WT[CZ * CZ];      // 32768 B, A-frag order
  const int t = threadIdx.x;
  const int lane = t & 63;
  const int wid = t >> 6;
  const int n16 = lane & 15;
  const int quad = lane >> 4;   // also LN row-group
  const int rowBase = blockIdx.x * 128;

  // ---- LayerNorm ----
  const int c0 = n16 * 8;
  float g8[8], b8[8];
  ld8<F32>(gma, c0, g8);
  ld8<F32>(bta, c0, b8);
  for (int it = 0; it < 8; ++it) {
    const int rl = wid * 32 + it * 4 + quad;
    float x[8];
    ld8<F32>(z, (size_t)(rowBase + rl) * CZ + c0, x);
    float s = 0.f, q2 = 0.f;
    #pragma unroll
    for (int u = 0; u < 8; ++u) { s += x[u]; q2 += x[u] * x[u]; }
    #pragma unroll
    for (int m = 1; m < 16; m <<= 1) {
      s  += __shfl_xor(s, m, 64);
      q2 += __shfl_xor(q2, m, 64);
    }
    const float mu = s * (1.0f / CZ);
    const float rs = rsqrtf(q2 * (1.0f / CZ) - mu * mu + 1e-5f);
    us8 o;
    #pragma unroll
    for (int u = 0; u < 8; ++u) o[u] = f2bf((x[u] - mu) * rs * g8[u] + b8[u]);
    *(us8*)&znl[rl * 136 + c0] = o;
  }
  __syncthreads();

  // ---- tri_bias (VALU; tiny). wb columns for this lane's channels in regs.
  float wb4[8][4];
  #pragma unroll
  for (int cc = 0; cc < 8; ++cc) ld4v<F32>(wbias, (size_t)(c0 + cc) * NH, wb4[cc]);
  for (int it = 0; it < 8; ++it) {
    const int rl = wid * 32 + it * 4 + quad;
    const us8 zv8 = *(const us8*)&znl[rl * 136 + c0];
    float a0 = 0.f, a1 = 0.f, a2 = 0.f, a3 = 0.f;
    #pragma unroll
    for (int cc = 0; cc < 8; ++cc) {
      const float zv = bf2f(zv8[cc]);
      a0 += zv * wb4[cc][0]; a1 += zv * wb4[cc][1];
      a2 += zv * wb4[cc][2]; a3 += zv * wb4[cc][3];
    }
    #pragma unroll
    for (int m = 1; m < 16; m <<= 1) {
      a0 += __shfl_xor(a0, m, 64); a1 += __shfl_xor(a1, m, 64);
      a2 += __shfl_xor(a2, m, 64); a3 += __shfl_xor(a3, m, 64);
    }
    if (n16 < 4) {
      const float v = (n16 == 0) ? a0 : (n16 == 1) ? a1 : (n16 == 2) ? a2 : a3;
      const int P = rowBase + rl;
      const int aI = P / NRES, bI = P % NRES;   // pair (qrow=aI, key=bI)
      triT[(size_t)n16 * NN + (size_t)bI * NRES + aI] = v;
    }
  }

  // ---- 4 projection GEMMs ----
  const u16 scl_q = 1;  // marker only
  for (int arr = 0; arr < 4; ++arr) {
    const void* W = (arr == 0) ? wq : (arr == 1) ? wk : (arr == 2) ? wv : wg;
    __syncthreads();   // prior MFMA reads of WT done
    #pragma unroll
    for (int it = 0; it < 16; ++it) {
      const int c = (t >> 5) + it * 8;
      const int m0 = (t & 31) * 4;
      float w4[4];
      ld4v<F32>(W, (size_t)c * CZ + m0, w4);
      const int ks = c >> 5, qq = (c >> 3) & 3, j = c & 7;
      #pragma unroll
      for (int mm = 0; mm < 4; ++mm) {
        const int m = m0 + mm;
        WT[ks * 4096 + (((m >> 4) * 4 + qq) * 16 + (m & 15)) * 8 + j] = f2bf(w4[mm]);
      }
    }
    __syncthreads();

    f4 acc[2][8];
    #pragma unroll
    for (int i = 0; i < 2; ++i)
      #pragma unroll
      for (int nt = 0; nt < 8; ++nt) acc[i][nt] = f4{0.f, 0.f, 0.f, 0.f};

    #pragma unroll
    for (int ks = 0; ks < 4; ++ks) {
      s8 a[2], b[8];
      #pragma unroll
      for (int i = 0; i < 2; ++i)
        a[i] = *(const s8*)&WT[ks * 4096 + (((wid * 2 + i) * 4 + quad) * 16 + n16) * 8];
      #pragma unroll
      for (int nt = 0; nt < 8; ++nt)
        b[nt] = *(const s8*)&znl[(nt * 16 + n16) * 136 + ks * 32 + quad * 8];
      #pragma unroll
      for (int i = 0; i < 2; ++i)
        #pragma unroll
        for (int nt = 0; nt < 8; ++nt)
          acc[i][nt] = __builtin_amdgcn_mfma_f32_16x16x32_bf16(a[i], b[nt], acc[i][nt], 0, 0, 0);
    }

    u16* dstb = (arr == 0) ? qb : (arr == 1) ? kb : (arr == 2) ? vb : gb;
    #pragma unroll
    for (int i = 0; i < 2; ++i) {
      const int mt = wid * 2 + i;
      const int och0 = mt * 16 + quad * 4;
      float e4[4];
      if (arr == 3) ld4v<F32>(bg, och0, e4);
      #pragma unroll
      for (int nt = 0; nt < 8; ++nt) {
        us4 o;
        #pragma unroll
        for (int r = 0; r < 4; ++r) {
          float v = acc[i][nt][r];
          if (arr == 0) v *= 0.17677669529663687f;           // CH^-0.5
          else if (arr == 3) v = 1.0f / (1.0f + __expf(-(v + e4[r])));
          o[r] = f2bf(v);
        }
        *(us4*)&dstb[(size_t)(rowBase + nt * 16 + n16) * CZ + och0] = o;
      }
    }
  }
  (void)scl_q;
}

// ---------------------------------------------------------------------------
// K2: MFMA attention, online softmax (exp2 domain), 2 q-tiles per wave.
//   R8: revert R7's two regressions (shared P buffer -> separate pbA/pbB,
//   cvt_pk asm -> shift-or RTNE pack); keep exp2 softmax + maskless path.
//   NEW: even/odd 2-chunk body — each half issues the NEXT half's tri float4
//   loads right after its own bias-add (tri regs dead by then), so the ~200cy
//   L2 latency hides under softmax+PV instead of sitting on the critical path.
//   LDS: 24576 (VB) + 10240 (Pch[4][2]) + 1536 (mbL) + 16 = 36368 B.
// ---------------------------------------------------------------------------
template<bool F32>
__global__ __launch_bounds__(256, 3) void k_attn(
    const u16* __restrict__ qb, const u16* __restrict__ kb, const u16* __restrict__ vb,
    const u16* __restrict__ gb, const float* __restrict__ triT, const void* __restrict__ msk,
    u16* __restrict__ ogb, const int* __restrict__ flag)
{
  if ((*flag != 0) != F32) return;
  __shared__ __align__(16) u16 VB[12 * 4 * 32 * 8];  // [sub32][quad][d][j], key-permuted
  __shared__ __align__(16) u16 Pch[4][2][16 * 40];   // per-wave, per-qtile P chunk
  __shared__ __align__(16) float mbL[NRES];          // mask bias per key (general path)
  __shared__ int anyM;
  const int t = threadIdx.x;
  const int i = blockIdx.x >> 2;
  const int h = blockIdx.x & 3;
  const size_t base_i = (size_t)i * NRES;

  if (t == 0) anyM = 0;
  __syncthreads();

  #pragma unroll
  for (int it = 0; it < 12; ++it) {
    const int idx = t + it * 256;
    const int kk = idx >> 3;
    const int d0 = (idx & 7) * 4;
    const us4 vv = *(const us4*)&vb[(base_i + kk) * CZ + h * CH + d0];
    const int cc2 = kk >> 5;
    const int kap = kk & 31;
    const int p = 2 * (kap & 15) + (kap >> 4);   // key-interleave position
    u16* vdst = &VB[((cc2 * 4 + (p >> 3)) * 32 + d0) * 8 + (p & 7)];
    vdst[0] = vv[0]; vdst[8] = vv[1]; vdst[16] = vv[2]; vdst[24] = vv[3];
  }
  {
    int loc = 0;
    for (int idx = t; idx < NRES; idx += 256) {
      const float mb = 1.0e9f * (ld1<F32>(msk, base_i + idx) - 1.0f);
      mbL[idx] = mb;
      if (mb != 0.0f) loc = 1;
    }
    if (loc) atomicOr(&anyM, 1);
  }
  __syncthreads();
  const bool masked = (anyM != 0);

  const int wid = t >> 6;
  const int lane = t & 63;
  const int n = lane & 15;
  const int quad = lane >> 4;
  const float* trih = triT + (size_t)h * NN;
  u16* pbA = &Pch[wid][0][0];
  u16* pbB = &Pch[wid][1][0];

  for (int pr = wid; pr < 12; pr += 4) {
    const int jrowA = pr * 32;
    const int jrowB = jrowA + 16;
    const s8 aqA = *(const s8*)&qb[(base_i + jrowA + n) * CZ + h * CH + quad * 8];
    const s8 aqB = *(const s8*)&qb[(base_i + jrowB + n) * CZ + h * CH + quad * 8];

    f4 O0A = {0.f,0.f,0.f,0.f}, O1A = {0.f,0.f,0.f,0.f};
    f4 O0B = {0.f,0.f,0.f,0.f}, O1B = {0.f,0.f,0.f,0.f};
    f4 lA = {0.f,0.f,0.f,0.f}, lB = {0.f,0.f,0.f,0.f};
    f4 nmA = {3.0e38f, 3.0e38f, 3.0e38f, 3.0e38f};   // negm2 = -max*L2E
    f4 nmB = {3.0e38f, 3.0e38f, 3.0e38f, 3.0e38f};

    // preload K chunk 0 + tri chunk 0
    s8 bk[4];
    f4 tCA[4], tCB[4];   // tri for the chunk about to be processed
    #pragma unroll
    for (int u = 0; u < 4; ++u)
      bk[u] = *(const s8*)&kb[(base_i + u * 16 + n) * CZ + h * CH + quad * 8];
    #pragma unroll
    for (int u = 0; u < 4; ++u) {
      const size_t trow = (size_t)(u * 16 + n) * NRES;
      tCA[u] = *(const f4*)&trih[trow + jrowA + quad * 4];
      tCB[u] = *(const f4*)&trih[trow + jrowB + quad * 4];
    }

    #pragma unroll 1
    for (int c = 0; c < 3; ++c) {
      #pragma unroll
      for (int half = 0; half < 2; ++half) {
        const int e = 2 * c + half;          // chunk index 0..5
        // ---- QK^T for 4 key tiles (64 keys), both q-tiles ----
        f4 SA[4], SB[4];
        #pragma unroll
        for (int u = 0; u < 4; ++u) {
          const f4 z4 = {0.f, 0.f, 0.f, 0.f};
          SA[u] = __builtin_amdgcn_mfma_f32_16x16x32_bf16(aqA, bk[u], z4, 0, 0, 0);
          SB[u] = __builtin_amdgcn_mfma_f32_16x16x32_bf16(aqB, bk[u], z4, 0, 0, 0);
        }
        // ---- prefetch next chunk's K ----
        if (e < 5) {
          #pragma unroll
          for (int u = 0; u < 4; ++u)
            bk[u] = *(const s8*)&kb[(base_i + ((e + 1) * 4 + u) * 16 + n) * CZ + h * CH + quad * 8];
        }
        // ---- bias: current tri regs (+mask); tri regs die here ----
        #pragma unroll
        for (int u = 0; u < 4; ++u) {
          #pragma unroll
          for (int r = 0; r < 4; ++r) { SA[u][r] += tCA[u][r]; SB[u][r] += tCB[u][r]; }
        }
        if (masked) {
          #pragma unroll
          for (int u = 0; u < 4; ++u) {
            const float mbv = mbL[(e * 4 + u) * 16 + n];
            #pragma unroll
            for (int r = 0; r < 4; ++r) { SA[u][r] += mbv; SB[u][r] += mbv; }
          }
        }
        // ---- issue next chunk's tri loads (latency hides under SM+PV) ----
        if (e < 5) {
          #pragma unroll
          for (int u = 0; u < 4; ++u) {
            const size_t trow = (size_t)(((e + 1) * 4 + u) * 16 + n) * NRES;
            tCA[u] = *(const f4*)&trih[trow + jrowA + quad * 4];
            tCB[u] = *(const f4*)&trih[trow + jrowB + quad * 4];
          }
        }
        // ---- chunk max -> exp2-domain running state ----
        f4 mxA, mxB;
        #pragma unroll
        for (int r = 0; r < 4; ++r) {
          mxA[r] = fmaxf(fmaxf(SA[0][r], SA[1][r]), fmaxf(SA[2][r], SA[3][r]));
          mxB[r] = fmaxf(fmaxf(SB[0][r], SB[1][r]), fmaxf(SB[2][r], SB[3][r]));
        }
        #pragma unroll
        for (int sft = 1; sft < 16; sft <<= 1) {
          #pragma unroll
          for (int r = 0; r < 4; ++r) {
            mxA[r] = fmaxf(mxA[r], __shfl_xor(mxA[r], sft, 64));
            mxB[r] = fmaxf(mxB[r], __shfl_xor(mxB[r], sft, 64));
          }
        }
        #pragma unroll
        for (int r = 0; r < 4; ++r) {
          const float nmAn = fminf(nmA[r], mxA[r] * (-L2E));
          const float scA = __builtin_exp2f(nmAn - nmA[r]);
          nmA[r] = nmAn;
          O0A[r] *= scA; O1A[r] *= scA; lA[r] *= scA;
          const float nmBn = fminf(nmB[r], mxB[r] * (-L2E));
          const float scB = __builtin_exp2f(nmBn - nmB[r]);
          nmB[r] = nmBn;
          O0B[r] *= scB; O1B[r] *= scB; lB[r] *= scB;
        }
        #pragma unroll
        for (int u = 0; u < 4; ++u) {
          #pragma unroll
          for (int r = 0; r < 4; ++r) {
            SA[u][r] = __builtin_exp2f(__builtin_fmaf(SA[u][r], L2E, nmA[r]));
            lA[r] += SA[u][r];
            SB[u][r] = __builtin_exp2f(__builtin_fmaf(SB[u][r], L2E, nmB[r]));
            lB[r] += SB[u][r];
          }
        }
        // ---- P pack (shift-or) -> LDS -> PV; separate pbA/pbB ----
        #pragma unroll
        for (int s = 0; s < 2; ++s) {
          #pragma unroll
          for (int r = 0; r < 4; ++r) {
            const unsigned wA = (unsigned)f2bf(SA[2 * s][r]) |
                                ((unsigned)f2bf(SA[2 * s + 1][r]) << 16);
            *(unsigned*)&pbA[(quad * 4 + r) * 40 + n * 2] = wA;
            const unsigned wB = (unsigned)f2bf(SB[2 * s][r]) |
                                ((unsigned)f2bf(SB[2 * s + 1][r]) << 16);
            *(unsigned*)&pbB[(quad * 4 + r) * 40 + n * 2] = wB;
          }
          const int C = e * 2 + s;
          const s8 apA = *(const s8*)&pbA[n * 40 + quad * 8];
          const s8 apB = *(const s8*)&pbB[n * 40 + quad * 8];
          const s8 bv0 = *(const s8*)&VB[((C * 4 + quad) * 32 + n) * 8];
          const s8 bv1 = *(const s8*)&VB[((C * 4 + quad) * 32 + 16 + n) * 8];
          O0A = __builtin_amdgcn_mfma_f32_16x16x32_bf16(apA, bv0, O0A, 0, 0, 0);
          O1A = __builtin_amdgcn_mfma_f32_16x16x32_bf16(apA, bv1, O1A, 0, 0, 0);
          O0B = __builtin_amdgcn_mfma_f32_16x16x32_bf16(apB, bv0, O0B, 0, 0, 0);
          O1B = __builtin_amdgcn_mfma_f32_16x16x32_bf16(apB, bv1, O1B, 0, 0, 0);
        }
      }
    }

    // ---- finish: sum-reduce over the 16-lane key axis, gate, store ----
    f4 sA = lA, sB = lB;
    #pragma unroll
    for (int sft = 1; sft < 16; sft <<= 1) {
      #pragma unroll
      for (int r = 0; r < 4; ++r) {
        sA[r] += __shfl_xor(sA[r], sft, 64);
        sB[r] += __shfl_xor(sB[r], sft, 64);
      }
    }
    #pragma unroll
    for (int r = 0; r < 4; ++r) {
      const float ivA = 1.0f / sA[r];
      const size_t rowA = (base_i + jrowA + quad * 4 + r) * CZ + h * CH;
      const float gA0 = bf2f(gb[rowA + n]);
      const float gA1 = bf2f(gb[rowA + 16 + n]);
      ogb[rowA + n]      = f2bf(O0A[r] * ivA * gA0);
      ogb[rowA + 16 + n] = f2bf(O1A[r] * ivA * gA1);
      const float ivB = 1.0f / sB[r];
      const size_t rowB = (base_i + jrowB + quad * 4 + r) * CZ + h * CH;
      const float gB0 = bf2f(gb[rowB + n]);
      const float gB1 = bf2f(gb[rowB + 16 + n]);
      ogb[rowB + n]      = f2bf(O0B[r] * ivB * gB0);
      ogb[rowB + 16 + n] = f2bf(O1B[r] * ivB * gB1);
    }
  }
}

// ---------------------------------------------------------------------------
// K3: out = (o*g) @ w_o + b_o — same MFMA structure as one k_ln_proj weight.
// (unchanged)
// ---------------------------------------------------------------------------
template<bool F32>
__global__ __launch_bounds__(256, 2) void k_out(
    const u16* __restrict__ og, const void* __restrict__ wo, const void* __restrict__ bo,
    void* __restrict__ outp, const int* __restrict__ flag)
{
  if ((*flag != 0) != F32) return;
  __shared__ __align__(16) u16 ol[128 * 136];
  __shared__ __align__(16) u16 WT[CZ * CZ];
  const int t = threadIdx.x;
  const int lane = t & 63;
  const int wid = t >> 6;
  const int n16 = lane & 15;
  const int quad = lane >> 4;
  const int rowBase = blockIdx.x * 128;

  #pragma unroll
  for (int it = 0; it < 8; ++it) {
    const int idx8 = t + it * 256;
    const int r = idx8 >> 4;
    const int c0 = (idx8 & 15) * 8;
    *(us8*)&ol[r * 136 + c0] = *(const us8*)&og[(size_t)(rowBase + r) * CZ + c0];
  }
  #pragma unroll
  for (int it = 0; it < 16; ++it) {
    const int c = (t >> 5) + it * 8;
    const int m0 = (t & 31) * 4;
    float w4[4];
    ld4v<F32>(wo, (size_t)c * CZ + m0, w4);
    const int ks = c >> 5, qq = (c >> 3) & 3, j = c & 7;
    #pragma unroll
    for (int mm = 0; mm < 4; ++mm) {
      const int m = m0 + mm;
      WT[ks * 4096 + (((m >> 4) * 4 + qq) * 16 + (m & 15)) * 8 + j] = f2bf(w4[mm]);
    }
  }
  __syncthreads();

  f4 acc[2][8];
  #pragma unroll
  for (int i = 0; i < 2; ++i)
    #pragma unroll
    for (int nt = 0; nt < 8; ++nt) acc[i][nt] = f4{0.f, 0.f, 0.f, 0.f};

  #pragma unroll
  for (int ks = 0; ks < 4; ++ks) {
    s8 a[2], b[8];
    #pragma unroll
    for (int i = 0; i < 2; ++i)
      a[i] = *(const s8*)&WT[ks * 4096 + (((wid * 2 + i) * 4 + quad) * 16 + n16) * 8];
    #pragma unroll
    for (int nt = 0; nt < 8; ++nt)
      b[nt] = *(const s8*)&ol[(nt * 16 + n16) * 136 + ks * 32 + quad * 8];
    #pragma unroll
    for (int i = 0; i < 2; ++i)
      #pragma unroll
      for (int nt = 0; nt < 8; ++nt)
        acc[i][nt] = __builtin_amdgcn_mfma_f32_16x16x32_bf16(a[i], b[nt], acc[i][nt], 0, 0, 0);
  }

  #pragma unroll
  for (int i = 0; i < 2; ++i) {
    const int och0 = (wid * 2 + i) * 16 + quad * 4;
    float b4[4];
    ld4v<F32>(bo, och0, b4);
    #pragma unroll
    for (int nt = 0; nt < 8; ++nt) {
      const size_t off = (size_t)(rowBase + nt * 16 + n16) * CZ + och0;
      if constexpr (F32) {
        float4 o;
        o.x = acc[i][nt][0] + b4[0]; o.y = acc[i][nt][1] + b4[1];
        o.z = acc[i][nt][2] + b4[2]; o.w = acc[i][nt][3] + b4[3];
        *(float4*)&((float*)outp)[off] = o;
      } else {
        us4 o;
        #pragma unroll
        for (int r = 0; r < 4; ++r) o[r] = f2bf(acc[i][nt][r] + b4[r]);
        *(us4*)&((u16*)outp)[off] = o;
      }
    }
  }
}

extern "C" void kernel_launch(void* const* d_in, const int* in_sizes, int n_in,
                              void* d_out, int out_size, void* d_ws, size_t ws_size,
                              hipStream_t stream) {
  const void* z     = d_in[0];
  const void* msk   = d_in[1];
  const void* gma   = d_in[2];
  const void* bta   = d_in[3];
  const void* wbias = d_in[4];
  const void* wq    = d_in[5];
  const void* wk    = d_in[6];
  const void* wv    = d_in[7];
  const void* wg    = d_in[8];
  const void* bg    = d_in[9];
  const void* wo    = d_in[10];
  const void* bo    = d_in[11];

  char* ws = (char*)d_ws;
  int* flag = (int*)ws;
  u16* qb = (u16*)(ws + 256);
  u16* kb = qb + NNCZ;
  u16* vb = kb + NNCZ;
  u16* gb = vb + NNCZ;
  float* triT = (float*)(gb + NNCZ);
  u16* ogb = qb;  // alias: q slice consumed by the same wave-iteration that writes o

  k_probe<<<dim3(1), dim3(64), 0, stream>>>((const u16*)z, flag);

  k_ln_proj<false><<<dim3(NN / 128), dim3(256), 0, stream>>>(
      z, gma, bta, wbias, wq, wk, wv, wg, bg, qb, kb, vb, gb, triT, flag);
  k_ln_proj<true><<<dim3(NN / 128), dim3(256), 0, stream>>>(
      z, gma, bta, wbias, wq, wk, wv, wg, bg, qb, kb, vb, gb, triT, flag);

  k_attn<false><<<dim3(NRES * NH), dim3(256), 0, stream>>>(
      qb, kb, vb, gb, triT, msk, ogb, flag);
  k_attn<true><<<dim3(NRES * NH), dim3(256), 0, stream>>>(
      qb, kb, vb, gb, triT, msk, ogb, flag);

  k_out<false><<<dim3(NN / 128), dim3(256), 0, stream>>>(ogb, wo, bo, d_out, flag);
  k_out<true><<<dim3(NN / 128), dim3(256), 0, stream>>>(ogb, wo, bo, d_out, flag);
}

// Round 9
// 538.319 us; speedup vs baseline: 1.1181x; 1.1181x over previous
//
#include <hip/hip_runtime.h>

#define NRES 384
#define CZ 128
#define NH 4
#define CH 32
#define NN (NRES * NRES)
#define NNCZ ((size_t)NN * CZ)

typedef unsigned short u16;
typedef __attribute__((ext_vector_type(4))) unsigned short us4;
typedef __attribute__((ext_vector_type(8))) unsigned short us8;
typedef __attribute__((ext_vector_type(8))) short s8;   // 8 bf16 = MFMA A/B frag
typedef __attribute__((ext_vector_type(4))) float f4;   // MFMA C/D frag

__device__ __forceinline__ float bf2f(u16 u) {
  return __uint_as_float(((unsigned)u) << 16);
}
__device__ __forceinline__ u16 f2bf(float f) {
  unsigned u = __float_as_uint(f);
  u += 0x7fffu + ((u >> 16) & 1u);  // RTNE
  return (u16)(u >> 16);
}

template<bool F32>
__device__ __forceinline__ float ld1(const void* p, size_t i) {
  if constexpr (F32) return ((const float*)p)[i];
  else return bf2f(((const u16*)p)[i]);
}

template<bool F32>
__device__ __forceinline__ void ld4v(const void* p, size_t i, float o[4]) {
  if constexpr (F32) {
    const float4 a = *(const float4*)((const float*)p + i);
    o[0] = a.x; o[1] = a.y; o[2] = a.z; o[3] = a.w;
  } else {
    const us4 v = *(const us4*)((const u16*)p + i);
    #pragma unroll
    for (int u = 0; u < 4; ++u) o[u] = bf2f(v[u]);
  }
}

template<bool F32>
__device__ __forceinline__ void ld8(const void* p, size_t i, float o[8]) {
  if constexpr (F32) {
    const float4 a = *(const float4*)((const float*)p + i);
    const float4 b = *(const float4*)((const float*)p + i + 4);
    o[0] = a.x; o[1] = a.y; o[2] = a.z; o[3] = a.w;
    o[4] = b.x; o[5] = b.y; o[6] = b.z; o[7] = b.w;
  } else {
    const us8 v = *(const us8*)((const u16*)p + i);
    #pragma unroll
    for (int u = 0; u < 8; ++u) o[u] = bf2f(v[u]);
  }
}

// ---------------------------------------------------------------------------
// Probe: decide input dtype from z's exponent-bit statistics.
// ---------------------------------------------------------------------------
__global__ void k_probe(const u16* __restrict__ z, int* __restrict__ flag) {
  int weird = 0;
  for (int i = threadIdx.x; i < 256; i += 64) {
    const int e = (z[i] >> 7) & 0xFF;
    if (e < 0x70 || e > 0x8F) weird++;
  }
  #pragma unroll
  for (int m = 1; m < 64; m <<= 1) weird += __shfl_xor(weird, m, 64);
  if (threadIdx.x == 0) *flag = (weird >= 16) ? 1 : 0;
}

// ---------------------------------------------------------------------------
// K1: LayerNorm + MFMA projections + tri_bias (transposed out).
//   R9: 64-row blocks (was 128). LDS 17408 (znl) + 32768 (WT) = 50176 B
//   -> 3 blocks/CU (was 2), grid 2304 = 3.0 exact rounds of 768 resident
//   (was 2.25 rounds -> 25% tail at half load). Weight staging runs 2x more
//   often but weights are 16KB L2-hot.
// ---------------------------------------------------------------------------
template<bool F32>
__global__ __launch_bounds__(256, 3) void k_ln_proj(
    const void* __restrict__ z, const void* __restrict__ gma, const void* __restrict__ bta,
    const void* __restrict__ wbias, const void* __restrict__ wq, const void* __restrict__ wk,
    const void* __restrict__ wv, const void* __restrict__ wg, const void* __restrict__ bg,
    u16* __restrict__ qb, u16* __restrict__ kb, u16* __restrict__ vb, u16* __restrict__ gb,
    float* __restrict__ triT, const int* __restrict__ flag)
{
  if ((*flag != 0) != F32) return;
  __shared__ __align__(16) u16 znl[64 * 136];    // 17408 B
  __shared__ __align__(16) u16 WT[CZ * CZ];      // 32768 B, A-frag order
  const int t = threadIdx.x;
  const int lane = t & 63;
  const int wid = t >> 6;
  const int n16 = lane & 15;
  const int quad = lane >> 4;   // also LN row-group
  const int rowBase = blockIdx.x * 64;

  // ---- LayerNorm (64 rows: wave covers 16) ----
  const int c0 = n16 * 8;
  float g8[8], b8[8];
  ld8<F32>(gma, c0, g8);
  ld8<F32>(bta, c0, b8);
  for (int it = 0; it < 4; ++it) {
    const int rl = wid * 16 + it * 4 + quad;
    float x[8];
    ld8<F32>(z, (size_t)(rowBase + rl) * CZ + c0, x);
    float s = 0.f, q2 = 0.f;
    #pragma unroll
    for (int u = 0; u < 8; ++u) { s += x[u]; q2 += x[u] * x[u]; }
    #pragma unroll
    for (int m = 1; m < 16; m <<= 1) {
      s  += __shfl_xor(s, m, 64);
      q2 += __shfl_xor(q2, m, 64);
    }
    const float mu = s * (1.0f / CZ);
    const float rs = rsqrtf(q2 * (1.0f / CZ) - mu * mu + 1e-5f);
    us8 o;
    #pragma unroll
    for (int u = 0; u < 8; ++u) o[u] = f2bf((x[u] - mu) * rs * g8[u] + b8[u]);
    *(us8*)&znl[rl * 136 + c0] = o;
  }
  __syncthreads();

  // ---- tri_bias (VALU; tiny). wb columns for this lane's channels in regs.
  float wb4[8][4];
  #pragma unroll
  for (int cc = 0; cc < 8; ++cc) ld4v<F32>(wbias, (size_t)(c0 + cc) * NH, wb4[cc]);
  for (int it = 0; it < 4; ++it) {
    const int rl = wid * 16 + it * 4 + quad;
    const us8 zv8 = *(const us8*)&znl[rl * 136 + c0];
    float a0 = 0.f, a1 = 0.f, a2 = 0.f, a3 = 0.f;
    #pragma unroll
    for (int cc = 0; cc < 8; ++cc) {
      const float zv = bf2f(zv8[cc]);
      a0 += zv * wb4[cc][0]; a1 += zv * wb4[cc][1];
      a2 += zv * wb4[cc][2]; a3 += zv * wb4[cc][3];
    }
    #pragma unroll
    for (int m = 1; m < 16; m <<= 1) {
      a0 += __shfl_xor(a0, m, 64); a1 += __shfl_xor(a1, m, 64);
      a2 += __shfl_xor(a2, m, 64); a3 += __shfl_xor(a3, m, 64);
    }
    if (n16 < 4) {
      const float v = (n16 == 0) ? a0 : (n16 == 1) ? a1 : (n16 == 2) ? a2 : a3;
      const int P = rowBase + rl;
      const int aI = P / NRES, bI = P % NRES;   // pair (qrow=aI, key=bI)
      triT[(size_t)n16 * NN + (size_t)bI * NRES + aI] = v;
    }
  }

  // ---- 4 projection GEMMs ----
  for (int arr = 0; arr < 4; ++arr) {
    const void* W = (arr == 0) ? wq : (arr == 1) ? wk : (arr == 2) ? wv : wg;
    __syncthreads();   // prior MFMA reads of WT done
    #pragma unroll
    for (int it = 0; it < 16; ++it) {
      const int c = (t >> 5) + it * 8;
      const int m0 = (t & 31) * 4;
      float w4[4];
      ld4v<F32>(W, (size_t)c * CZ + m0, w4);
      const int ks = c >> 5, qq = (c >> 3) & 3, j = c & 7;
      #pragma unroll
      for (int mm = 0; mm < 4; ++mm) {
        const int m = m0 + mm;
        WT[ks * 4096 + (((m >> 4) * 4 + qq) * 16 + (m & 15)) * 8 + j] = f2bf(w4[mm]);
      }
    }
    __syncthreads();

    f4 acc[2][4];
    #pragma unroll
    for (int i = 0; i < 2; ++i)
      #pragma unroll
      for (int nt = 0; nt < 4; ++nt) acc[i][nt] = f4{0.f, 0.f, 0.f, 0.f};

    #pragma unroll
    for (int ks = 0; ks < 4; ++ks) {
      s8 a[2], b[4];
      #pragma unroll
      for (int i = 0; i < 2; ++i)
        a[i] = *(const s8*)&WT[ks * 4096 + (((wid * 2 + i) * 4 + quad) * 16 + n16) * 8];
      #pragma unroll
      for (int nt = 0; nt < 4; ++nt)
        b[nt] = *(const s8*)&znl[(nt * 16 + n16) * 136 + ks * 32 + quad * 8];
      #pragma unroll
      for (int i = 0; i < 2; ++i)
        #pragma unroll
        for (int nt = 0; nt < 4; ++nt)
          acc[i][nt] = __builtin_amdgcn_mfma_f32_16x16x32_bf16(a[i], b[nt], acc[i][nt], 0, 0, 0);
    }

    u16* dstb = (arr == 0) ? qb : (arr == 1) ? kb : (arr == 2) ? vb : gb;
    #pragma unroll
    for (int i = 0; i < 2; ++i) {
      const int mt = wid * 2 + i;
      const int och0 = mt * 16 + quad * 4;
      float e4[4];
      if (arr == 3) ld4v<F32>(bg, och0, e4);
      #pragma unroll
      for (int nt = 0; nt < 4; ++nt) {
        us4 o;
        #pragma unroll
        for (int r = 0; r < 4; ++r) {
          float v = acc[i][nt][r];
          if (arr == 0) v *= 0.17677669529663687f;           // CH^-0.5
          else if (arr == 3) v = 1.0f / (1.0f + __expf(-(v + e4[r])));
          o[r] = f2bf(v);
        }
        *(us4*)&dstb[(size_t)(rowBase + nt * 16 + n16) * CZ + och0] = o;
      }
    }
  }
}

// ---------------------------------------------------------------------------
// K2: MFMA attention (exact R4 config — best measured: 206us, 84 VGPR,
// zero spill). Online softmax, 2 q-tiles/wave, 64-key chunks, K reg-prefetch.
// Lesson from R5-R8: live set must stay < ~85 VGPRs or hipcc spills rather
// than allocating more. Do not add register state to this kernel.
//   LDS: 24576 (VB) + 10240 (Pch[4][2]) + 1536 (mbL) = 36352 B.
// ---------------------------------------------------------------------------
template<bool F32>
__global__ __launch_bounds__(256, 3) void k_attn(
    const u16* __restrict__ qb, const u16* __restrict__ kb, const u16* __restrict__ vb,
    const u16* __restrict__ gb, const float* __restrict__ triT, const void* __restrict__ msk,
    u16* __restrict__ ogb, const int* __restrict__ flag)
{
  if ((*flag != 0) != F32) return;
  __shared__ __align__(16) u16 VB[12 * 4 * 32 * 8];  // [sub32][quad][d][j], key-permuted
  __shared__ __align__(16) u16 Pch[4][2][16 * 40];   // per-wave, per-qtile P chunk
  __shared__ __align__(16) float mbL[NRES];          // mask bias per key
  const int t = threadIdx.x;
  const int i = blockIdx.x >> 2;
  const int h = blockIdx.x & 3;
  const size_t base_i = (size_t)i * NRES;

  #pragma unroll
  for (int it = 0; it < 12; ++it) {
    const int idx = t + it * 256;
    const int kk = idx >> 3;
    const int d0 = (idx & 7) * 4;
    const us4 vv = *(const us4*)&vb[(base_i + kk) * CZ + h * CH + d0];
    const int cc2 = kk >> 5;
    const int kap = kk & 31;
    const int p = 2 * (kap & 15) + (kap >> 4);   // key-interleave position
    u16* vdst = &VB[((cc2 * 4 + (p >> 3)) * 32 + d0) * 8 + (p & 7)];
    vdst[0] = vv[0]; vdst[8] = vv[1]; vdst[16] = vv[2]; vdst[24] = vv[3];
  }
  for (int idx = t; idx < NRES; idx += 256)
    mbL[idx] = 1.0e9f * (ld1<F32>(msk, base_i + idx) - 1.0f);
  __syncthreads();

  const int wid = t >> 6;
  const int lane = t & 63;
  const int n = lane & 15;
  const int quad = lane >> 4;
  const float* trih = triT + (size_t)h * NN;
  u16* pbA = &Pch[wid][0][0];
  u16* pbB = &Pch[wid][1][0];

  for (int pr = wid; pr < 12; pr += 4) {
    const int jrowA = pr * 32;
    const int jrowB = jrowA + 16;
    const s8 aqA = *(const s8*)&qb[(base_i + jrowA + n) * CZ + h * CH + quad * 8];
    const s8 aqB = *(const s8*)&qb[(base_i + jrowB + n) * CZ + h * CH + quad * 8];

    f4 O0A = {0.f,0.f,0.f,0.f}, O1A = {0.f,0.f,0.f,0.f};
    f4 O0B = {0.f,0.f,0.f,0.f}, O1B = {0.f,0.f,0.f,0.f};
    f4 lA = {0.f,0.f,0.f,0.f}, lB = {0.f,0.f,0.f,0.f};
    f4 mA = {-1.0e30f,-1.0e30f,-1.0e30f,-1.0e30f};
    f4 mB = {-1.0e30f,-1.0e30f,-1.0e30f,-1.0e30f};

    // preload K chunk 0
    s8 bk[4];
    #pragma unroll
    for (int u = 0; u < 4; ++u)
      bk[u] = *(const s8*)&kb[(base_i + u * 16 + n) * CZ + h * CH + quad * 8];

    #pragma unroll 1
    for (int cc = 0; cc < 6; ++cc) {
      // ---- QK^T for 4 key tiles (64 keys), both q-tiles ----
      f4 SA[4], SB[4];
      #pragma unroll
      for (int u = 0; u < 4; ++u) {
        const f4 z4 = {0.f, 0.f, 0.f, 0.f};
        SA[u] = __builtin_amdgcn_mfma_f32_16x16x32_bf16(aqA, bk[u], z4, 0, 0, 0);
        SB[u] = __builtin_amdgcn_mfma_f32_16x16x32_bf16(aqB, bk[u], z4, 0, 0, 0);
      }
      // ---- prefetch next chunk's K (hidden under softmax+PV) ----
      if (cc < 5) {
        #pragma unroll
        for (int u = 0; u < 4; ++u)
          bk[u] = *(const s8*)&kb[(base_i + ((cc + 1) * 4 + u) * 16 + n) * CZ + h * CH + quad * 8];
      }
      // ---- bias: tri (f32 float4, paired lines) + mask (LDS broadcast) ----
      #pragma unroll
      for (int u = 0; u < 4; ++u) {
        const int tt = cc * 4 + u;
        const float mbv = mbL[tt * 16 + n];
        const size_t trow = (size_t)(tt * 16 + n) * NRES;
        const float4 tA = *(const float4*)&trih[trow + jrowA + quad * 4];
        const float4 tB = *(const float4*)&trih[trow + jrowB + quad * 4];
        SA[u][0] += tA.x + mbv; SA[u][1] += tA.y + mbv;
        SA[u][2] += tA.z + mbv; SA[u][3] += tA.w + mbv;
        SB[u][0] += tB.x + mbv; SB[u][1] += tB.y + mbv;
        SB[u][2] += tB.z + mbv; SB[u][3] += tB.w + mbv;
      }
      // ---- online softmax: chunk max, rescale running state ----
      f4 mxA = SA[0], mxB = SB[0];
      #pragma unroll
      for (int u = 1; u < 4; ++u) {
        #pragma unroll
        for (int r = 0; r < 4; ++r) {
          mxA[r] = fmaxf(mxA[r], SA[u][r]);
          mxB[r] = fmaxf(mxB[r], SB[u][r]);
        }
      }
      #pragma unroll
      for (int sft = 1; sft < 16; sft <<= 1) {
        #pragma unroll
        for (int r = 0; r < 4; ++r) {
          mxA[r] = fmaxf(mxA[r], __shfl_xor(mxA[r], sft, 64));
          mxB[r] = fmaxf(mxB[r], __shfl_xor(mxB[r], sft, 64));
        }
      }
      #pragma unroll
      for (int r = 0; r < 4; ++r) {
        const float mnA = fmaxf(mA[r], mxA[r]);
        const float scA = __expf(mA[r] - mnA);
        mA[r] = mnA;
        O0A[r] *= scA; O1A[r] *= scA; lA[r] *= scA;
        const float mnB = fmaxf(mB[r], mxB[r]);
        const float scB = __expf(mB[r] - mnB);
        mB[r] = mnB;
        O0B[r] *= scB; O1B[r] *= scB; lB[r] *= scB;
      }
      #pragma unroll
      for (int u = 0; u < 4; ++u) {
        #pragma unroll
        for (int r = 0; r < 4; ++r) {
          SA[u][r] = __expf(SA[u][r] - mA[r]);
          lA[r] += SA[u][r];
          SB[u][r] = __expf(SB[u][r] - mB[r]);
          lB[r] += SB[u][r];
        }
      }
      // ---- P pack -> LDS -> PV, 2 sub-chunks of 32 keys; V frags shared ----
      #pragma unroll
      for (int s = 0; s < 2; ++s) {
        #pragma unroll
        for (int r = 0; r < 4; ++r) {
          const unsigned wA = (unsigned)f2bf(SA[2 * s][r]) |
                              ((unsigned)f2bf(SA[2 * s + 1][r]) << 16);
          *(unsigned*)&pbA[(quad * 4 + r) * 40 + n * 2] = wA;
          const unsigned wB = (unsigned)f2bf(SB[2 * s][r]) |
                              ((unsigned)f2bf(SB[2 * s + 1][r]) << 16);
          *(unsigned*)&pbB[(quad * 4 + r) * 40 + n * 2] = wB;
        }
        const int C = cc * 2 + s;
        const s8 apA = *(const s8*)&pbA[n * 40 + quad * 8];
        const s8 apB = *(const s8*)&pbB[n * 40 + quad * 8];
        const s8 bv0 = *(const s8*)&VB[((C * 4 + quad) * 32 + n) * 8];
        const s8 bv1 = *(const s8*)&VB[((C * 4 + quad) * 32 + 16 + n) * 8];
        O0A = __builtin_amdgcn_mfma_f32_16x16x32_bf16(apA, bv0, O0A, 0, 0, 0);
        O1A = __builtin_amdgcn_mfma_f32_16x16x32_bf16(apA, bv1, O1A, 0, 0, 0);
        O0B = __builtin_amdgcn_mfma_f32_16x16x32_bf16(apB, bv0, O0B, 0, 0, 0);
        O1B = __builtin_amdgcn_mfma_f32_16x16x32_bf16(apB, bv1, O1B, 0, 0, 0);
      }
    }

    // ---- finish: sum-reduce over the 16-lane key axis, gate, store ----
    f4 sA = lA, sB = lB;
    #pragma unroll
    for (int sft = 1; sft < 16; sft <<= 1) {
      #pragma unroll
      for (int r = 0; r < 4; ++r) {
        sA[r] += __shfl_xor(sA[r], sft, 64);
        sB[r] += __shfl_xor(sB[r], sft, 64);
      }
    }
    #pragma unroll
    for (int r = 0; r < 4; ++r) {
      const float ivA = 1.0f / sA[r];
      const size_t rowA = (base_i + jrowA + quad * 4 + r) * CZ + h * CH;
      const float gA0 = bf2f(gb[rowA + n]);
      const float gA1 = bf2f(gb[rowA + 16 + n]);
      ogb[rowA + n]      = f2bf(O0A[r] * ivA * gA0);
      ogb[rowA + 16 + n] = f2bf(O1A[r] * ivA * gA1);
      const float ivB = 1.0f / sB[r];
      const size_t rowB = (base_i + jrowB + quad * 4 + r) * CZ + h * CH;
      const float gB0 = bf2f(gb[rowB + n]);
      const float gB1 = bf2f(gb[rowB + 16 + n]);
      ogb[rowB + n]      = f2bf(O0B[r] * ivB * gB0);
      ogb[rowB + 16 + n] = f2bf(O1B[r] * ivB * gB1);
    }
  }
}

// ---------------------------------------------------------------------------
// K3: out = (o*g) @ w_o + b_o.
//   R9: 64-row blocks (was 128) — same occupancy/tail fix as K1.
//   LDS 17408 (ol) + 32768 (WT) = 50176 B -> 3 blocks/CU, grid 2304.
// ---------------------------------------------------------------------------
template<bool F32>
__global__ __launch_bounds__(256, 3) void k_out(
    const u16* __restrict__ og, const void* __restrict__ wo, const void* __restrict__ bo,
    void* __restrict__ outp, const int* __restrict__ flag)
{
  if ((*flag != 0) != F32) return;
  __shared__ __align__(16) u16 ol[64 * 136];
  __shared__ __align__(16) u16 WT[CZ * CZ];
  const int t = threadIdx.x;
  const int lane = t & 63;
  const int wid = t >> 6;
  const int n16 = lane & 15;
  const int quad = lane >> 4;
  const int rowBase = blockIdx.x * 64;

  #pragma unroll
  for (int it = 0; it < 4; ++it) {
    const int idx8 = t + it * 256;
    const int r = idx8 >> 4;
    const int c0 = (idx8 & 15) * 8;
    *(us8*)&ol[r * 136 + c0] = *(const us8*)&og[(size_t)(rowBase + r) * CZ + c0];
  }
  #pragma unroll
  for (int it = 0; it < 16; ++it) {
    const int c = (t >> 5) + it * 8;
    const int m0 = (t & 31) * 4;
    float w4[4];
    ld4v<F32>(wo, (size_t)c * CZ + m0, w4);
    const int ks = c >> 5, qq = (c >> 3) & 3, j = c & 7;
    #pragma unroll
    for (int mm = 0; mm < 4; ++mm) {
      const int m = m0 + mm;
      WT[ks * 4096 + (((m >> 4) * 4 + qq) * 16 + (m & 15)) * 8 + j] = f2bf(w4[mm]);
    }
  }
  __syncthreads();

  f4 acc[2][4];
  #pragma unroll
  for (int i = 0; i < 2; ++i)
    #pragma unroll
    for (int nt = 0; nt < 4; ++nt) acc[i][nt] = f4{0.f, 0.f, 0.f, 0.f};

  #pragma unroll
  for (int ks = 0; ks < 4; ++ks) {
    s8 a[2], b[4];
    #pragma unroll
    for (int i = 0; i < 2; ++i)
      a[i] = *(const s8*)&WT[ks * 4096 + (((wid * 2 + i) * 4 + quad) * 16 + n16) * 8];
    #pragma unroll
    for (int nt = 0; nt < 4; ++nt)
      b[nt] = *(const s8*)&ol[(nt * 16 + n16) * 136 + ks * 32 + quad * 8];
    #pragma unroll
    for (int i = 0; i < 2; ++i)
      #pragma unroll
      for (int nt = 0; nt < 4; ++nt)
        acc[i][nt] = __builtin_amdgcn_mfma_f32_16x16x32_bf16(a[i], b[nt], acc[i][nt], 0, 0, 0);
  }

  #pragma unroll
  for (int i = 0; i < 2; ++i) {
    const int och0 = (wid * 2 + i) * 16 + quad * 4;
    float b4[4];
    ld4v<F32>(bo, och0, b4);
    #pragma unroll
    for (int nt = 0; nt < 4; ++nt) {
      const size_t off = (size_t)(rowBase + nt * 16 + n16) * CZ + och0;
      if constexpr (F32) {
        float4 o;
        o.x = acc[i][nt][0] + b4[0]; o.y = acc[i][nt][1] + b4[1];
        o.z = acc[i][nt][2] + b4[2]; o.w = acc[i][nt][3] + b4[3];
        *(float4*)&((float*)outp)[off] = o;
      } else {
        us4 o;
        #pragma unroll
        for (int r = 0; r < 4; ++r) o[r] = f2bf(acc[i][nt][r] + b4[r]);
        *(us4*)&((u16*)outp)[off] = o;
      }
    }
  }
}

extern "C" void kernel_launch(void* const* d_in, const int* in_sizes, int n_in,
                              void* d_out, int out_size, void* d_ws, size_t ws_size,
                              hipStream_t stream) {
  const void* z     = d_in[0];
  const void* msk   = d_in[1];
  const void* gma   = d_in[2];
  const void* bta   = d_in[3];
  const void* wbias = d_in[4];
  const void* wq    = d_in[5];
  const void* wk    = d_in[6];
  const void* wv    = d_in[7];
  const void* wg    = d_in[8];
  const void* bg    = d_in[9];
  const void* wo    = d_in[10];
  const void* bo    = d_in[11];

  char* ws = (char*)d_ws;
  int* flag = (int*)ws;
  u16* qb = (u16*)(ws + 256);
  u16* kb = qb + NNCZ;
  u16* vb = kb + NNCZ;
  u16* gb = vb + NNCZ;
  float* triT = (float*)(gb + NNCZ);
  u16* ogb = qb;  // alias: q slice consumed by the same wave-iteration that writes o

  k_probe<<<dim3(1), dim3(64), 0, stream>>>((const u16*)z, flag);

  k_ln_proj<false><<<dim3(NN / 64), dim3(256), 0, stream>>>(
      z, gma, bta, wbias, wq, wk, wv, wg, bg, qb, kb, vb, gb, triT, flag);
  k_ln_proj<true><<<dim3(NN / 64), dim3(256), 0, stream>>>(
      z, gma, bta, wbias, wq, wk, wv, wg, bg, qb, kb, vb, gb, triT, flag);

  k_attn<false><<<dim3(NRES * NH), dim3(256), 0, stream>>>(
      qb, kb, vb, gb, triT, msk, ogb, flag);
  k_attn<true><<<dim3(NRES * NH), dim3(256), 0, stream>>>(
      qb, kb, vb, gb, triT, msk, ogb, flag);

  k_out<false><<<dim3(NN / 64), dim3(256), 0, stream>>>(ogb, wo, bo, d_out, flag);
  k_out<true><<<dim3(NN / 64), dim3(256), 0, stream>>>(ogb, wo, bo, d_out, flag);
}

// Round 10
// 437.765 us; speedup vs baseline: 1.3750x; 1.2297x over previous
//
#include <hip/hip_runtime.h>

#define NRES 384
#define CZ 128
#define NH 4
#define CH 32
#define NN (NRES * NRES)
#define NNCZ ((size_t)NN * CZ)

typedef unsigned short u16;
typedef __attribute__((ext_vector_type(4))) unsigned short us4;
typedef __attribute__((ext_vector_type(8))) unsigned short us8;
typedef __attribute__((ext_vector_type(8))) short s8;   // 8 bf16 = MFMA A/B frag
typedef __attribute__((ext_vector_type(4))) float f4;   // MFMA C/D frag

__device__ __forceinline__ float bf2f(u16 u) {
  return __uint_as_float(((unsigned)u) << 16);
}
__device__ __forceinline__ u16 f2bf(float f) {
  unsigned u = __float_as_uint(f);
  u += 0x7fffu + ((u >> 16) & 1u);  // RTNE
  return (u16)(u >> 16);
}

template<bool F32>
__device__ __forceinline__ float ld1(const void* p, size_t i) {
  if constexpr (F32) return ((const float*)p)[i];
  else return bf2f(((const u16*)p)[i]);
}

template<bool F32>
__device__ __forceinline__ void ld4v(const void* p, size_t i, float o[4]) {
  if constexpr (F32) {
    const float4 a = *(const float4*)((const float*)p + i);
    o[0] = a.x; o[1] = a.y; o[2] = a.z; o[3] = a.w;
  } else {
    const us4 v = *(const us4*)((const u16*)p + i);
    #pragma unroll
    for (int u = 0; u < 4; ++u) o[u] = bf2f(v[u]);
  }
}

template<bool F32>
__device__ __forceinline__ void ld8(const void* p, size_t i, float o[8]) {
  if constexpr (F32) {
    const float4 a = *(const float4*)((const float*)p + i);
    const float4 b = *(const float4*)((const float*)p + i + 4);
    o[0] = a.x; o[1] = a.y; o[2] = a.z; o[3] = a.w;
    o[4] = b.x; o[5] = b.y; o[6] = b.z; o[7] = b.w;
  } else {
    const us8 v = *(const us8*)((const u16*)p + i);
    #pragma unroll
    for (int u = 0; u < 8; ++u) o[u] = bf2f(v[u]);
  }
}

// ---------------------------------------------------------------------------
// Probe: decide input dtype from z's exponent-bit statistics.
// ---------------------------------------------------------------------------
__global__ void k_probe(const u16* __restrict__ z, int* __restrict__ flag) {
  int weird = 0;
  for (int i = threadIdx.x; i < 256; i += 64) {
    const int e = (z[i] >> 7) & 0xFF;
    if (e < 0x70 || e > 0x8F) weird++;
  }
  #pragma unroll
  for (int m = 1; m < 64; m <<= 1) weird += __shfl_xor(weird, m, 64);
  if (threadIdx.x == 0) *flag = (weird >= 16) ? 1 : 0;
}

// ---------------------------------------------------------------------------
// K0: one-time weight repack into A-fragment order (bf16, workspace).
//   dst[a] layout identical to the old per-block WT staging:
//   elem (m=outch, k=c) at [ks*4096 + (((m>>4)*4+qq)*16+(m&15))*8 + j],
//   c = ks*32 + qq*8 + j. 5 arrays: wq, wk, wv, wg, wo (16384 u16 each).
// ---------------------------------------------------------------------------
template<bool F32>
__global__ void k_repack(const void* __restrict__ w0, const void* __restrict__ w1,
                         const void* __restrict__ w2, const void* __restrict__ w3,
                         const void* __restrict__ w4p, u16* __restrict__ dst,
                         const int* __restrict__ flag) {
  if ((*flag != 0) != F32) return;
  const int a = blockIdx.x;   // 0..4
  const void* W = (a == 0) ? w0 : (a == 1) ? w1 : (a == 2) ? w2 : (a == 3) ? w3 : w4p;
  u16* d = dst + (size_t)a * 16384;
  const int t = threadIdx.x;
  #pragma unroll
  for (int it = 0; it < 16; ++it) {
    const int c = (t >> 5) + it * 8;
    const int m0 = (t & 31) * 4;
    float w4[4];
    ld4v<F32>(W, (size_t)c * CZ + m0, w4);
    const int ks = c >> 5, qq = (c >> 3) & 3, j = c & 7;
    #pragma unroll
    for (int mm = 0; mm < 4; ++mm) {
      const int m = m0 + mm;
      d[ks * 4096 + (((m >> 4) * 4 + qq) * 16 + (m & 15)) * 8 + j] = f2bf(w4[mm]);
    }
  }
}

// ---------------------------------------------------------------------------
// K1: LayerNorm + MFMA projections + tri_bias (transposed out).
//   R10: weights pre-repacked in workspace (k_repack) — no WT LDS, no
//   per-array staging loops, no per-array barriers. A-fragments read
//   straight from global (32KB/array, L2-resident everywhere).
//   LDS = znl only 34816 B -> up to 4 blocks/CU (was 2).
// ---------------------------------------------------------------------------
template<bool F32>
__global__ __launch_bounds__(256, 2) void k_ln_proj(
    const void* __restrict__ z, const void* __restrict__ gma, const void* __restrict__ bta,
    const void* __restrict__ wbias, const u16* __restrict__ wrep, const void* __restrict__ bg,
    u16* __restrict__ qb, u16* __restrict__ kb, u16* __restrict__ vb, u16* __restrict__ gb,
    float* __restrict__ triT, const int* __restrict__ flag)
{
  if ((*flag != 0) != F32) return;
  __shared__ __align__(16) u16 znl[128 * 136];   // 34816 B (only LDS)
  const int t = threadIdx.x;
  const int lane = t & 63;
  const int wid = t >> 6;
  const int n16 = lane & 15;
  const int quad = lane >> 4;   // also LN row-group
  const int rowBase = blockIdx.x * 128;

  // ---- LayerNorm ----
  const int c0 = n16 * 8;
  float g8[8], b8[8];
  ld8<F32>(gma, c0, g8);
  ld8<F32>(bta, c0, b8);
  for (int it = 0; it < 8; ++it) {
    const int rl = wid * 32 + it * 4 + quad;
    float x[8];
    ld8<F32>(z, (size_t)(rowBase + rl) * CZ + c0, x);
    float s = 0.f, q2 = 0.f;
    #pragma unroll
    for (int u = 0; u < 8; ++u) { s += x[u]; q2 += x[u] * x[u]; }
    #pragma unroll
    for (int m = 1; m < 16; m <<= 1) {
      s  += __shfl_xor(s, m, 64);
      q2 += __shfl_xor(q2, m, 64);
    }
    const float mu = s * (1.0f / CZ);
    const float rs = rsqrtf(q2 * (1.0f / CZ) - mu * mu + 1e-5f);
    us8 o;
    #pragma unroll
    for (int u = 0; u < 8; ++u) o[u] = f2bf((x[u] - mu) * rs * g8[u] + b8[u]);
    *(us8*)&znl[rl * 136 + c0] = o;
  }
  __syncthreads();

  // ---- tri_bias (VALU; tiny). wb columns for this lane's channels in regs.
  float wb4[8][4];
  #pragma unroll
  for (int cc = 0; cc < 8; ++cc) ld4v<F32>(wbias, (size_t)(c0 + cc) * NH, wb4[cc]);
  for (int it = 0; it < 8; ++it) {
    const int rl = wid * 32 + it * 4 + quad;
    const us8 zv8 = *(const us8*)&znl[rl * 136 + c0];
    float a0 = 0.f, a1 = 0.f, a2 = 0.f, a3 = 0.f;
    #pragma unroll
    for (int cc = 0; cc < 8; ++cc) {
      const float zv = bf2f(zv8[cc]);
      a0 += zv * wb4[cc][0]; a1 += zv * wb4[cc][1];
      a2 += zv * wb4[cc][2]; a3 += zv * wb4[cc][3];
    }
    #pragma unroll
    for (int m = 1; m < 16; m <<= 1) {
      a0 += __shfl_xor(a0, m, 64); a1 += __shfl_xor(a1, m, 64);
      a2 += __shfl_xor(a2, m, 64); a3 += __shfl_xor(a3, m, 64);
    }
    if (n16 < 4) {
      const float v = (n16 == 0) ? a0 : (n16 == 1) ? a1 : (n16 == 2) ? a2 : a3;
      const int P = rowBase + rl;
      const int aI = P / NRES, bI = P % NRES;   // pair (qrow=aI, key=bI)
      triT[(size_t)n16 * NN + (size_t)bI * NRES + aI] = v;
    }
  }

  // ---- 4 projection GEMMs, weights from repacked global ----
  for (int arr = 0; arr < 4; ++arr) {
    const u16* WTg = wrep + (size_t)arr * 16384;

    f4 acc[2][8];
    #pragma unroll
    for (int i = 0; i < 2; ++i)
      #pragma unroll
      for (int nt = 0; nt < 8; ++nt) acc[i][nt] = f4{0.f, 0.f, 0.f, 0.f};

    #pragma unroll
    for (int ks = 0; ks < 4; ++ks) {
      s8 a[2], b[8];
      #pragma unroll
      for (int i = 0; i < 2; ++i)
        a[i] = *(const s8*)&WTg[ks * 4096 + (((wid * 2 + i) * 4 + quad) * 16 + n16) * 8];
      #pragma unroll
      for (int nt = 0; nt < 8; ++nt)
        b[nt] = *(const s8*)&znl[(nt * 16 + n16) * 136 + ks * 32 + quad * 8];
      #pragma unroll
      for (int i = 0; i < 2; ++i)
        #pragma unroll
        for (int nt = 0; nt < 8; ++nt)
          acc[i][nt] = __builtin_amdgcn_mfma_f32_16x16x32_bf16(a[i], b[nt], acc[i][nt], 0, 0, 0);
    }

    u16* dstb = (arr == 0) ? qb : (arr == 1) ? kb : (arr == 2) ? vb : gb;
    #pragma unroll
    for (int i = 0; i < 2; ++i) {
      const int mt = wid * 2 + i;
      const int och0 = mt * 16 + quad * 4;
      float e4[4];
      if (arr == 3) ld4v<F32>(bg, och0, e4);
      #pragma unroll
      for (int nt = 0; nt < 8; ++nt) {
        us4 o;
        #pragma unroll
        for (int r = 0; r < 4; ++r) {
          float v = acc[i][nt][r];
          if (arr == 0) v *= 0.17677669529663687f;           // CH^-0.5
          else if (arr == 3) v = 1.0f / (1.0f + __expf(-(v + e4[r])));
          o[r] = f2bf(v);
        }
        *(us4*)&dstb[(size_t)(rowBase + nt * 16 + n16) * CZ + och0] = o;
      }
    }
  }
}

// ---------------------------------------------------------------------------
// K2: MFMA attention (exact R4 config — best measured: 206us, 84 VGPR,
// zero spill). Online softmax, 2 q-tiles/wave, 64-key chunks, K reg-prefetch.
// Lesson from R5-R8: live set must stay < ~85 VGPRs or hipcc spills rather
// than allocating more. Do not add register state to this kernel.
//   LDS: 24576 (VB) + 10240 (Pch[4][2]) + 1536 (mbL) = 36352 B.
// ---------------------------------------------------------------------------
template<bool F32>
__global__ __launch_bounds__(256, 3) void k_attn(
    const u16* __restrict__ qb, const u16* __restrict__ kb, const u16* __restrict__ vb,
    const u16* __restrict__ gb, const float* __restrict__ triT, const void* __restrict__ msk,
    u16* __restrict__ ogb, const int* __restrict__ flag)
{
  if ((*flag != 0) != F32) return;
  __shared__ __align__(16) u16 VB[12 * 4 * 32 * 8];  // [sub32][quad][d][j], key-permuted
  __shared__ __align__(16) u16 Pch[4][2][16 * 40];   // per-wave, per-qtile P chunk
  __shared__ __align__(16) float mbL[NRES];          // mask bias per key
  const int t = threadIdx.x;
  const int i = blockIdx.x >> 2;
  const int h = blockIdx.x & 3;
  const size_t base_i = (size_t)i * NRES;

  #pragma unroll
  for (int it = 0; it < 12; ++it) {
    const int idx = t + it * 256;
    const int kk = idx >> 3;
    const int d0 = (idx & 7) * 4;
    const us4 vv = *(const us4*)&vb[(base_i + kk) * CZ + h * CH + d0];
    const int cc2 = kk >> 5;
    const int kap = kk & 31;
    const int p = 2 * (kap & 15) + (kap >> 4);   // key-interleave position
    u16* vdst = &VB[((cc2 * 4 + (p >> 3)) * 32 + d0) * 8 + (p & 7)];
    vdst[0] = vv[0]; vdst[8] = vv[1]; vdst[16] = vv[2]; vdst[24] = vv[3];
  }
  for (int idx = t; idx < NRES; idx += 256)
    mbL[idx] = 1.0e9f * (ld1<F32>(msk, base_i + idx) - 1.0f);
  __syncthreads();

  const int wid = t >> 6;
  const int lane = t & 63;
  const int n = lane & 15;
  const int quad = lane >> 4;
  const float* trih = triT + (size_t)h * NN;
  u16* pbA = &Pch[wid][0][0];
  u16* pbB = &Pch[wid][1][0];

  for (int pr = wid; pr < 12; pr += 4) {
    const int jrowA = pr * 32;
    const int jrowB = jrowA + 16;
    const s8 aqA = *(const s8*)&qb[(base_i + jrowA + n) * CZ + h * CH + quad * 8];
    const s8 aqB = *(const s8*)&qb[(base_i + jrowB + n) * CZ + h * CH + quad * 8];

    f4 O0A = {0.f,0.f,0.f,0.f}, O1A = {0.f,0.f,0.f,0.f};
    f4 O0B = {0.f,0.f,0.f,0.f}, O1B = {0.f,0.f,0.f,0.f};
    f4 lA = {0.f,0.f,0.f,0.f}, lB = {0.f,0.f,0.f,0.f};
    f4 mA = {-1.0e30f,-1.0e30f,-1.0e30f,-1.0e30f};
    f4 mB = {-1.0e30f,-1.0e30f,-1.0e30f,-1.0e30f};

    // preload K chunk 0
    s8 bk[4];
    #pragma unroll
    for (int u = 0; u < 4; ++u)
      bk[u] = *(const s8*)&kb[(base_i + u * 16 + n) * CZ + h * CH + quad * 8];

    #pragma unroll 1
    for (int cc = 0; cc < 6; ++cc) {
      // ---- QK^T for 4 key tiles (64 keys), both q-tiles ----
      f4 SA[4], SB[4];
      #pragma unroll
      for (int u = 0; u < 4; ++u) {
        const f4 z4 = {0.f, 0.f, 0.f, 0.f};
        SA[u] = __builtin_amdgcn_mfma_f32_16x16x32_bf16(aqA, bk[u], z4, 0, 0, 0);
        SB[u] = __builtin_amdgcn_mfma_f32_16x16x32_bf16(aqB, bk[u], z4, 0, 0, 0);
      }
      // ---- prefetch next chunk's K (hidden under softmax+PV) ----
      if (cc < 5) {
        #pragma unroll
        for (int u = 0; u < 4; ++u)
          bk[u] = *(const s8*)&kb[(base_i + ((cc + 1) * 4 + u) * 16 + n) * CZ + h * CH + quad * 8];
      }
      // ---- bias: tri (f32 float4, paired lines) + mask (LDS broadcast) ----
      #pragma unroll
      for (int u = 0; u < 4; ++u) {
        const int tt = cc * 4 + u;
        const float mbv = mbL[tt * 16 + n];
        const size_t trow = (size_t)(tt * 16 + n) * NRES;
        const float4 tA = *(const float4*)&trih[trow + jrowA + quad * 4];
        const float4 tB = *(const float4*)&trih[trow + jrowB + quad * 4];
        SA[u][0] += tA.x + mbv; SA[u][1] += tA.y + mbv;
        SA[u][2] += tA.z + mbv; SA[u][3] += tA.w + mbv;
        SB[u][0] += tB.x + mbv; SB[u][1] += tB.y + mbv;
        SB[u][2] += tB.z + mbv; SB[u][3] += tB.w + mbv;
      }
      // ---- online softmax: chunk max, rescale running state ----
      f4 mxA = SA[0], mxB = SB[0];
      #pragma unroll
      for (int u = 1; u < 4; ++u) {
        #pragma unroll
        for (int r = 0; r < 4; ++r) {
          mxA[r] = fmaxf(mxA[r], SA[u][r]);
          mxB[r] = fmaxf(mxB[r], SB[u][r]);
        }
      }
      #pragma unroll
      for (int sft = 1; sft < 16; sft <<= 1) {
        #pragma unroll
        for (int r = 0; r < 4; ++r) {
          mxA[r] = fmaxf(mxA[r], __shfl_xor(mxA[r], sft, 64));
          mxB[r] = fmaxf(mxB[r], __shfl_xor(mxB[r], sft, 64));
        }
      }
      #pragma unroll
      for (int r = 0; r < 4; ++r) {
        const float mnA = fmaxf(mA[r], mxA[r]);
        const float scA = __expf(mA[r] - mnA);
        mA[r] = mnA;
        O0A[r] *= scA; O1A[r] *= scA; lA[r] *= scA;
        const float mnB = fmaxf(mB[r], mxB[r]);
        const float scB = __expf(mB[r] - mnB);
        mB[r] = mnB;
        O0B[r] *= scB; O1B[r] *= scB; lB[r] *= scB;
      }
      #pragma unroll
      for (int u = 0; u < 4; ++u) {
        #pragma unroll
        for (int r = 0; r < 4; ++r) {
          SA[u][r] = __expf(SA[u][r] - mA[r]);
          lA[r] += SA[u][r];
          SB[u][r] = __expf(SB[u][r] - mB[r]);
          lB[r] += SB[u][r];
        }
      }
      // ---- P pack -> LDS -> PV, 2 sub-chunks of 32 keys; V frags shared ----
      #pragma unroll
      for (int s = 0; s < 2; ++s) {
        #pragma unroll
        for (int r = 0; r < 4; ++r) {
          const unsigned wA = (unsigned)f2bf(SA[2 * s][r]) |
                              ((unsigned)f2bf(SA[2 * s + 1][r]) << 16);
          *(unsigned*)&pbA[(quad * 4 + r) * 40 + n * 2] = wA;
          const unsigned wB = (unsigned)f2bf(SB[2 * s][r]) |
                              ((unsigned)f2bf(SB[2 * s + 1][r]) << 16);
          *(unsigned*)&pbB[(quad * 4 + r) * 40 + n * 2] = wB;
        }
        const int C = cc * 2 + s;
        const s8 apA = *(const s8*)&pbA[n * 40 + quad * 8];
        const s8 apB = *(const s8*)&pbB[n * 40 + quad * 8];
        const s8 bv0 = *(const s8*)&VB[((C * 4 + quad) * 32 + n) * 8];
        const s8 bv1 = *(const s8*)&VB[((C * 4 + quad) * 32 + 16 + n) * 8];
        O0A = __builtin_amdgcn_mfma_f32_16x16x32_bf16(apA, bv0, O0A, 0, 0, 0);
        O1A = __builtin_amdgcn_mfma_f32_16x16x32_bf16(apA, bv1, O1A, 0, 0, 0);
        O0B = __builtin_amdgcn_mfma_f32_16x16x32_bf16(apB, bv0, O0B, 0, 0, 0);
        O1B = __builtin_amdgcn_mfma_f32_16x16x32_bf16(apB, bv1, O1B, 0, 0, 0);
      }
    }

    // ---- finish: sum-reduce over the 16-lane key axis, gate, store ----
    f4 sA = lA, sB = lB;
    #pragma unroll
    for (int sft = 1; sft < 16; sft <<= 1) {
      #pragma unroll
      for (int r = 0; r < 4; ++r) {
        sA[r] += __shfl_xor(sA[r], sft, 64);
        sB[r] += __shfl_xor(sB[r], sft, 64);
      }
    }
    #pragma unroll
    for (int r = 0; r < 4; ++r) {
      const float ivA = 1.0f / sA[r];
      const size_t rowA = (base_i + jrowA + quad * 4 + r) * CZ + h * CH;
      const float gA0 = bf2f(gb[rowA + n]);
      const float gA1 = bf2f(gb[rowA + 16 + n]);
      ogb[rowA + n]      = f2bf(O0A[r] * ivA * gA0);
      ogb[rowA + 16 + n] = f2bf(O1A[r] * ivA * gA1);
      const float ivB = 1.0f / sB[r];
      const size_t rowB = (base_i + jrowB + quad * 4 + r) * CZ + h * CH;
      const float gB0 = bf2f(gb[rowB + n]);
      const float gB1 = bf2f(gb[rowB + 16 + n]);
      ogb[rowB + n]      = f2bf(O0B[r] * ivB * gB0);
      ogb[rowB + 16 + n] = f2bf(O1B[r] * ivB * gB1);
    }
  }
}

// ---------------------------------------------------------------------------
// K3: out = (o*g) @ w_o + b_o.
//   R10: w_o pre-repacked (wrep+4*16384) — no WT LDS/staging/barrier pair.
//   LDS = ol only 34816 B -> up to 4 blocks/CU.
// ---------------------------------------------------------------------------
template<bool F32>
__global__ __launch_bounds__(256, 2) void k_out(
    const u16* __restrict__ og, const u16* __restrict__ wrep, const void* __restrict__ bo,
    void* __restrict__ outp, const int* __restrict__ flag)
{
  if ((*flag != 0) != F32) return;
  __shared__ __align__(16) u16 ol[128 * 136];
  const u16* WTg = wrep + (size_t)4 * 16384;
  const int t = threadIdx.x;
  const int lane = t & 63;
  const int wid = t >> 6;
  const int n16 = lane & 15;
  const int quad = lane >> 4;
  const int rowBase = blockIdx.x * 128;

  #pragma unroll
  for (int it = 0; it < 8; ++it) {
    const int idx8 = t + it * 256;
    const int r = idx8 >> 4;
    const int c0 = (idx8 & 15) * 8;
    *(us8*)&ol[r * 136 + c0] = *(const us8*)&og[(size_t)(rowBase + r) * CZ + c0];
  }
  __syncthreads();

  f4 acc[2][8];
  #pragma unroll
  for (int i = 0; i < 2; ++i)
    #pragma unroll
    for (int nt = 0; nt < 8; ++nt) acc[i][nt] = f4{0.f, 0.f, 0.f, 0.f};

  #pragma unroll
  for (int ks = 0; ks < 4; ++ks) {
    s8 a[2], b[8];
    #pragma unroll
    for (int i = 0; i < 2; ++i)
      a[i] = *(const s8*)&WTg[ks * 4096 + (((wid * 2 + i) * 4 + quad) * 16 + n16) * 8];
    #pragma unroll
    for (int nt = 0; nt < 8; ++nt)
      b[nt] = *(const s8*)&ol[(nt * 16 + n16) * 136 + ks * 32 + quad * 8];
    #pragma unroll
    for (int i = 0; i < 2; ++i)
      #pragma unroll
      for (int nt = 0; nt < 8; ++nt)
        acc[i][nt] = __builtin_amdgcn_mfma_f32_16x16x32_bf16(a[i], b[nt], acc[i][nt], 0, 0, 0);
  }

  #pragma unroll
  for (int i = 0; i < 2; ++i) {
    const int och0 = (wid * 2 + i) * 16 + quad * 4;
    float b4[4];
    ld4v<F32>(bo, och0, b4);
    #pragma unroll
    for (int nt = 0; nt < 8; ++nt) {
      const size_t off = (size_t)(rowBase + nt * 16 + n16) * CZ + och0;
      if constexpr (F32) {
        float4 o;
        o.x = acc[i][nt][0] + b4[0]; o.y = acc[i][nt][1] + b4[1];
        o.z = acc[i][nt][2] + b4[2]; o.w = acc[i][nt][3] + b4[3];
        *(float4*)&((float*)outp)[off] = o;
      } else {
        us4 o;
        #pragma unroll
        for (int r = 0; r < 4; ++r) o[r] = f2bf(acc[i][nt][r] + b4[r]);
        *(us4*)&((u16*)outp)[off] = o;
      }
    }
  }
}

extern "C" void kernel_launch(void* const* d_in, const int* in_sizes, int n_in,
                              void* d_out, int out_size, void* d_ws, size_t ws_size,
                              hipStream_t stream) {
  const void* z     = d_in[0];
  const void* msk   = d_in[1];
  const void* gma   = d_in[2];
  const void* bta   = d_in[3];
  const void* wbias = d_in[4];
  const void* wq    = d_in[5];
  const void* wk    = d_in[6];
  const void* wv    = d_in[7];
  const void* wg    = d_in[8];
  const void* bg    = d_in[9];
  const void* wo    = d_in[10];
  const void* bo    = d_in[11];

  char* ws = (char*)d_ws;
  int* flag = (int*)ws;
  u16* qb = (u16*)(ws + 256);
  u16* kb = qb + NNCZ;
  u16* vb = kb + NNCZ;
  u16* gb = vb + NNCZ;
  float* triT = (float*)(gb + NNCZ);
  u16* wrep = (u16*)(triT + (size_t)NH * NN);   // 5 * 16384 u16 = 160 KB
  u16* ogb = qb;  // alias: q slice consumed by the same wave-iteration that writes o

  k_probe<<<dim3(1), dim3(64), 0, stream>>>((const u16*)z, flag);

  k_repack<false><<<dim3(5), dim3(256), 0, stream>>>(wq, wk, wv, wg, wo, wrep, flag);
  k_repack<true><<<dim3(5), dim3(256), 0, stream>>>(wq, wk, wv, wg, wo, wrep, flag);

  k_ln_proj<false><<<dim3(NN / 128), dim3(256), 0, stream>>>(
      z, gma, bta, wbias, wrep, bg, qb, kb, vb, gb, triT, flag);
  k_ln_proj<true><<<dim3(NN / 128), dim3(256), 0, stream>>>(
      z, gma, bta, wbias, wrep, bg, qb, kb, vb, gb, triT, flag);

  k_attn<false><<<dim3(NRES * NH), dim3(256), 0, stream>>>(
      qb, kb, vb, gb, triT, msk, ogb, flag);
  k_attn<true><<<dim3(NRES * NH), dim3(256), 0, stream>>>(
      qb, kb, vb, gb, triT, msk, ogb, flag);

  k_out<false><<<dim3(NN / 128), dim3(256), 0, stream>>>(ogb, wrep, bo, d_out, flag);
  k_out<true><<<dim3(NN / 128), dim3(256), 0, stream>>>(ogb, wrep, bo, d_out, flag);
}

// Round 12
// 437.272 us; speedup vs baseline: 1.3765x; 1.0011x over previous
//
#include <hip/hip_runtime.h>

#define NRES 384
#define CZ 128
#define NH 4
#define CH 32
#define NN (NRES * NRES)
#define NNCZ ((size_t)NN * CZ)

typedef unsigned short u16;
typedef __attribute__((ext_vector_type(4))) unsigned short us4;
typedef __attribute__((ext_vector_type(8))) unsigned short us8;
typedef __attribute__((ext_vector_type(8))) short s8;   // 8 bf16 = MFMA A/B frag
typedef __attribute__((ext_vector_type(4))) float f4;   // MFMA C/D frag

__device__ __forceinline__ float bf2f(u16 u) {
  return __uint_as_float(((unsigned)u) << 16);
}
__device__ __forceinline__ u16 f2bf(float f) {
  unsigned u = __float_as_uint(f);
  u += 0x7fffu + ((u >> 16) & 1u);  // RTNE
  return (u16)(u >> 16);
}

template<bool F32>
__device__ __forceinline__ float ld1(const void* p, size_t i) {
  if constexpr (F32) return ((const float*)p)[i];
  else return bf2f(((const u16*)p)[i]);
}

template<bool F32>
__device__ __forceinline__ void ld4v(const void* p, size_t i, float o[4]) {
  if constexpr (F32) {
    const float4 a = *(const float4*)((const float*)p + i);
    o[0] = a.x; o[1] = a.y; o[2] = a.z; o[3] = a.w;
  } else {
    const us4 v = *(const us4*)((const u16*)p + i);
    #pragma unroll
    for (int u = 0; u < 4; ++u) o[u] = bf2f(v[u]);
  }
}

template<bool F32>
__device__ __forceinline__ void ld8(const void* p, size_t i, float o[8]) {
  if constexpr (F32) {
    const float4 a = *(const float4*)((const float*)p + i);
    const float4 b = *(const float4*)((const float*)p + i + 4);
    o[0] = a.x; o[1] = a.y; o[2] = a.z; o[3] = a.w;
    o[4] = b.x; o[5] = b.y; o[6] = b.z; o[7] = b.w;
  } else {
    const us8 v = *(const us8*)((const u16*)p + i);
    #pragma unroll
    for (int u = 0; u < 8; ++u) o[u] = bf2f(v[u]);
  }
}

// ---------------------------------------------------------------------------
// Probe: decide input dtype from z's exponent-bit statistics.
// ---------------------------------------------------------------------------
__global__ void k_probe(const u16* __restrict__ z, int* __restrict__ flag) {
  int weird = 0;
  for (int i = threadIdx.x; i < 256; i += 64) {
    const int e = (z[i] >> 7) & 0xFF;
    if (e < 0x70 || e > 0x8F) weird++;
  }
  #pragma unroll
  for (int m = 1; m < 64; m <<= 1) weird += __shfl_xor(weird, m, 64);
  if (threadIdx.x == 0) *flag = (weird >= 16) ? 1 : 0;
}

// ---------------------------------------------------------------------------
// K0: one-time weight repack into A-fragment order (bf16, workspace).
//   elem (m=outch, k=c) at [ks*4096 + (((m>>4)*4+qq)*16+(m&15))*8 + j],
//   c = ks*32 + qq*8 + j.
//   Arrays: 0=wq (q-scale folded), 1=wk, 2=wv, 3=wg, 4=wo,
//           5=w_bias padded 4->16 outch (zeros above h=3).
// ---------------------------------------------------------------------------
template<bool F32>
__global__ void k_repack(const void* __restrict__ w0, const void* __restrict__ w1,
                         const void* __restrict__ w2, const void* __restrict__ w3,
                         const void* __restrict__ w4p, const void* __restrict__ w5b,
                         u16* __restrict__ dst, const int* __restrict__ flag) {
  if ((*flag != 0) != F32) return;
  const int a = blockIdx.x;   // 0..5
  u16* d = dst + (size_t)a * 16384;
  const int t = threadIdx.x;
  if (a == 5) {
    #pragma unroll
    for (int it = 0; it < 16; ++it) {
      const int c = (t >> 5) + it * 8;
      const int m0 = (t & 31) * 4;
      float w4[4] = {0.f, 0.f, 0.f, 0.f};
      if (m0 == 0) ld4v<F32>(w5b, (size_t)c * NH, w4);   // wbias[c][0..3]
      const int ks = c >> 5, qq = (c >> 3) & 3, j = c & 7;
      #pragma unroll
      for (int mm = 0; mm < 4; ++mm) {
        const int m = m0 + mm;
        d[ks * 4096 + (((m >> 4) * 4 + qq) * 16 + (m & 15)) * 8 + j] = f2bf(w4[mm]);
      }
    }
    return;
  }
  const void* W = (a == 0) ? w0 : (a == 1) ? w1 : (a == 2) ? w2 : (a == 3) ? w3 : w4p;
  const float scl = (a == 0) ? 0.17677669529663687f : 1.0f;   // CH^-0.5 folded into wq
  #pragma unroll
  for (int it = 0; it < 16; ++it) {
    const int c = (t >> 5) + it * 8;
    const int m0 = (t & 31) * 4;
    float w4[4];
    ld4v<F32>(W, (size_t)c * CZ + m0, w4);
    const int ks = c >> 5, qq = (c >> 3) & 3, j = c & 7;
    #pragma unroll
    for (int mm = 0; mm < 4; ++mm) {
      const int m = m0 + mm;
      d[ks * 4096 + (((m >> 4) * 4 + qq) * 16 + (m & 15)) * 8 + j] = f2bf(w4[mm] * scl);
    }
  }
}

// ---------------------------------------------------------------------------
// K1: LayerNorm + MFMA projections + tri_bias (transposed out).
//   R12 (= R11 resubmit; infra flake): tri_bias via MFMA (w_bias repacked+
//   padded, array 5) — replaces the per-block shuffle storm (128 ds_swizzle
//   + 256 FMA) with 8 MFMA/wave. q-scale folded into repacked wq.
//   LDS = znl only, 34816 B.
// ---------------------------------------------------------------------------
template<bool F32>
__global__ __launch_bounds__(256, 2) void k_ln_proj(
    const void* __restrict__ z, const void* __restrict__ gma, const void* __restrict__ bta,
    const u16* __restrict__ wrep, const void* __restrict__ bg,
    u16* __restrict__ qb, u16* __restrict__ kb, u16* __restrict__ vb, u16* __restrict__ gb,
    float* __restrict__ triT, const int* __restrict__ flag)
{
  if ((*flag != 0) != F32) return;
  __shared__ __align__(16) u16 znl[128 * 136];   // 34816 B (only LDS)
  const int t = threadIdx.x;
  const int lane = t & 63;
  const int wid = t >> 6;
  const int n16 = lane & 15;
  const int quad = lane >> 4;   // also LN row-group
  const int rowBase = blockIdx.x * 128;

  // ---- LayerNorm ----
  const int c0 = n16 * 8;
  float g8[8], b8[8];
  ld8<F32>(gma, c0, g8);
  ld8<F32>(bta, c0, b8);
  for (int it = 0; it < 8; ++it) {
    const int rl = wid * 32 + it * 4 + quad;
    float x[8];
    ld8<F32>(z, (size_t)(rowBase + rl) * CZ + c0, x);
    float s = 0.f, q2 = 0.f;
    #pragma unroll
    for (int u = 0; u < 8; ++u) { s += x[u]; q2 += x[u] * x[u]; }
    #pragma unroll
    for (int m = 1; m < 16; m <<= 1) {
      s  += __shfl_xor(s, m, 64);
      q2 += __shfl_xor(q2, m, 64);
    }
    const float mu = s * (1.0f / CZ);
    const float rs = rsqrtf(q2 * (1.0f / CZ) - mu * mu + 1e-5f);
    us8 o;
    #pragma unroll
    for (int u = 0; u < 8; ++u) o[u] = f2bf((x[u] - mu) * rs * g8[u] + b8[u]);
    *(us8*)&znl[rl * 136 + c0] = o;
  }
  __syncthreads();

  // ---- tri_bias via MFMA: D = w_bias^T(padded) @ zn^T, rows 0..3 = heads ----
  {
    const u16* WTb = wrep + (size_t)5 * 16384;
    f4 acc2[2];
    acc2[0] = f4{0.f, 0.f, 0.f, 0.f};
    acc2[1] = f4{0.f, 0.f, 0.f, 0.f};
    #pragma unroll
    for (int ks = 0; ks < 4; ++ks) {
      const s8 ab = *(const s8*)&WTb[ks * 4096 + (quad * 16 + n16) * 8];  // mt=0
      #pragma unroll
      for (int i = 0; i < 2; ++i) {
        const s8 b = *(const s8*)&znl[((wid * 2 + i) * 16 + n16) * 136 + ks * 32 + quad * 8];
        acc2[i] = __builtin_amdgcn_mfma_f32_16x16x32_bf16(ab, b, acc2[i], 0, 0, 0);
      }
    }
    if (quad == 0) {
      #pragma unroll
      for (int i = 0; i < 2; ++i) {
        const int P = rowBase + (wid * 2 + i) * 16 + n16;
        const int aI = P / NRES, bI = P % NRES;   // pair (qrow=aI, key=bI)
        #pragma unroll
        for (int r = 0; r < 4; ++r)
          triT[(size_t)r * NN + (size_t)bI * NRES + aI] = acc2[i][r];
      }
    }
  }

  // ---- 4 projection GEMMs, weights from repacked global ----
  for (int arr = 0; arr < 4; ++arr) {
    const u16* WTg = wrep + (size_t)arr * 16384;

    f4 acc[2][8];
    #pragma unroll
    for (int i = 0; i < 2; ++i)
      #pragma unroll
      for (int nt = 0; nt < 8; ++nt) acc[i][nt] = f4{0.f, 0.f, 0.f, 0.f};

    #pragma unroll
    for (int ks = 0; ks < 4; ++ks) {
      s8 a[2], b[8];
      #pragma unroll
      for (int i = 0; i < 2; ++i)
        a[i] = *(const s8*)&WTg[ks * 4096 + (((wid * 2 + i) * 4 + quad) * 16 + n16) * 8];
      #pragma unroll
      for (int nt = 0; nt < 8; ++nt)
        b[nt] = *(const s8*)&znl[(nt * 16 + n16) * 136 + ks * 32 + quad * 8];
      #pragma unroll
      for (int i = 0; i < 2; ++i)
        #pragma unroll
        for (int nt = 0; nt < 8; ++nt)
          acc[i][nt] = __builtin_amdgcn_mfma_f32_16x16x32_bf16(a[i], b[nt], acc[i][nt], 0, 0, 0);
    }

    u16* dstb = (arr == 0) ? qb : (arr == 1) ? kb : (arr == 2) ? vb : gb;
    #pragma unroll
    for (int i = 0; i < 2; ++i) {
      const int mt = wid * 2 + i;
      const int och0 = mt * 16 + quad * 4;
      float e4[4];
      if (arr == 3) ld4v<F32>(bg, och0, e4);
      #pragma unroll
      for (int nt = 0; nt < 8; ++nt) {
        us4 o;
        #pragma unroll
        for (int r = 0; r < 4; ++r) {
          float v = acc[i][nt][r];
          if (arr == 3) v = 1.0f / (1.0f + __expf(-(v + e4[r])));
          o[r] = f2bf(v);
        }
        *(us4*)&dstb[(size_t)(rowBase + nt * 16 + n16) * CZ + och0] = o;
      }
    }
  }
}

// ---------------------------------------------------------------------------
// K2: MFMA attention (exact R4 config — best measured: 206us, 84 VGPR,
// zero spill). Online softmax, 2 q-tiles/wave, 64-key chunks, K reg-prefetch.
// Lesson from R5-R8: live set must stay < ~85 VGPRs or hipcc spills rather
// than allocating more. Do not add register state to this kernel.
//   LDS: 24576 (VB) + 10240 (Pch[4][2]) + 1536 (mbL) = 36352 B.
// ---------------------------------------------------------------------------
template<bool F32>
__global__ __launch_bounds__(256, 3) void k_attn(
    const u16* __restrict__ qb, const u16* __restrict__ kb, const u16* __restrict__ vb,
    const u16* __restrict__ gb, const float* __restrict__ triT, const void* __restrict__ msk,
    u16* __restrict__ ogb, const int* __restrict__ flag)
{
  if ((*flag != 0) != F32) return;
  __shared__ __align__(16) u16 VB[12 * 4 * 32 * 8];  // [sub32][quad][d][j], key-permuted
  __shared__ __align__(16) u16 Pch[4][2][16 * 40];   // per-wave, per-qtile P chunk
  __shared__ __align__(16) float mbL[NRES];          // mask bias per key
  const int t = threadIdx.x;
  const int i = blockIdx.x >> 2;
  const int h = blockIdx.x & 3;
  const size_t base_i = (size_t)i * NRES;

  #pragma unroll
  for (int it = 0; it < 12; ++it) {
    const int idx = t + it * 256;
    const int kk = idx >> 3;
    const int d0 = (idx & 7) * 4;
    const us4 vv = *(const us4*)&vb[(base_i + kk) * CZ + h * CH + d0];
    const int cc2 = kk >> 5;
    const int kap = kk & 31;
    const int p = 2 * (kap & 15) + (kap >> 4);   // key-interleave position
    u16* vdst = &VB[((cc2 * 4 + (p >> 3)) * 32 + d0) * 8 + (p & 7)];
    vdst[0] = vv[0]; vdst[8] = vv[1]; vdst[16] = vv[2]; vdst[24] = vv[3];
  }
  for (int idx = t; idx < NRES; idx += 256)
    mbL[idx] = 1.0e9f * (ld1<F32>(msk, base_i + idx) - 1.0f);
  __syncthreads();

  const int wid = t >> 6;
  const int lane = t & 63;
  const int n = lane & 15;
  const int quad = lane >> 4;
  const float* trih = triT + (size_t)h * NN;
  u16* pbA = &Pch[wid][0][0];
  u16* pbB = &Pch[wid][1][0];

  for (int pr = wid; pr < 12; pr += 4) {
    const int jrowA = pr * 32;
    const int jrowB = jrowA + 16;
    const s8 aqA = *(const s8*)&qb[(base_i + jrowA + n) * CZ + h * CH + quad * 8];
    const s8 aqB = *(const s8*)&qb[(base_i + jrowB + n) * CZ + h * CH + quad * 8];

    f4 O0A = {0.f,0.f,0.f,0.f}, O1A = {0.f,0.f,0.f,0.f};
    f4 O0B = {0.f,0.f,0.f,0.f}, O1B = {0.f,0.f,0.f,0.f};
    f4 lA = {0.f,0.f,0.f,0.f}, lB = {0.f,0.f,0.f,0.f};
    f4 mA = {-1.0e30f,-1.0e30f,-1.0e30f,-1.0e30f};
    f4 mB = {-1.0e30f,-1.0e30f,-1.0e30f,-1.0e30f};

    // preload K chunk 0
    s8 bk[4];
    #pragma unroll
    for (int u = 0; u < 4; ++u)
      bk[u] = *(const s8*)&kb[(base_i + u * 16 + n) * CZ + h * CH + quad * 8];

    #pragma unroll 1
    for (int cc = 0; cc < 6; ++cc) {
      // ---- QK^T for 4 key tiles (64 keys), both q-tiles ----
      f4 SA[4], SB[4];
      #pragma unroll
      for (int u = 0; u < 4; ++u) {
        const f4 z4 = {0.f, 0.f, 0.f, 0.f};
        SA[u] = __builtin_amdgcn_mfma_f32_16x16x32_bf16(aqA, bk[u], z4, 0, 0, 0);
        SB[u] = __builtin_amdgcn_mfma_f32_16x16x32_bf16(aqB, bk[u], z4, 0, 0, 0);
      }
      // ---- prefetch next chunk's K (hidden under softmax+PV) ----
      if (cc < 5) {
        #pragma unroll
        for (int u = 0; u < 4; ++u)
          bk[u] = *(const s8*)&kb[(base_i + ((cc + 1) * 4 + u) * 16 + n) * CZ + h * CH + quad * 8];
      }
      // ---- bias: tri (f32 float4, paired lines) + mask (LDS broadcast) ----
      #pragma unroll
      for (int u = 0; u < 4; ++u) {
        const int tt = cc * 4 + u;
        const float mbv = mbL[tt * 16 + n];
        const size_t trow = (size_t)(tt * 16 + n) * NRES;
        const float4 tA = *(const float4*)&trih[trow + jrowA + quad * 4];
        const float4 tB = *(const float4*)&trih[trow + jrowB + quad * 4];
        SA[u][0] += tA.x + mbv; SA[u][1] += tA.y + mbv;
        SA[u][2] += tA.z + mbv; SA[u][3] += tA.w + mbv;
        SB[u][0] += tB.x + mbv; SB[u][1] += tB.y + mbv;
        SB[u][2] += tB.z + mbv; SB[u][3] += tB.w + mbv;
      }
      // ---- online softmax: chunk max, rescale running state ----
      f4 mxA = SA[0], mxB = SB[0];
      #pragma unroll
      for (int u = 1; u < 4; ++u) {
        #pragma unroll
        for (int r = 0; r < 4; ++r) {
          mxA[r] = fmaxf(mxA[r], SA[u][r]);
          mxB[r] = fmaxf(mxB[r], SB[u][r]);
        }
      }
      #pragma unroll
      for (int sft = 1; sft < 16; sft <<= 1) {
        #pragma unroll
        for (int r = 0; r < 4; ++r) {
          mxA[r] = fmaxf(mxA[r], __shfl_xor(mxA[r], sft, 64));
          mxB[r] = fmaxf(mxB[r], __shfl_xor(mxB[r], sft, 64));
        }
      }
      #pragma unroll
      for (int r = 0; r < 4; ++r) {
        const float mnA = fmaxf(mA[r], mxA[r]);
        const float scA = __expf(mA[r] - mnA);
        mA[r] = mnA;
        O0A[r] *= scA; O1A[r] *= scA; lA[r] *= scA;
        const float mnB = fmaxf(mB[r], mxB[r]);
        const float scB = __expf(mB[r] - mnB);
        mB[r] = mnB;
        O0B[r] *= scB; O1B[r] *= scB; lB[r] *= scB;
      }
      #pragma unroll
      for (int u = 0; u < 4; ++u) {
        #pragma unroll
        for (int r = 0; r < 4; ++r) {
          SA[u][r] = __expf(SA[u][r] - mA[r]);
          lA[r] += SA[u][r];
          SB[u][r] = __expf(SB[u][r] - mB[r]);
          lB[r] += SB[u][r];
        }
      }
      // ---- P pack -> LDS -> PV, 2 sub-chunks of 32 keys; V frags shared ----
      #pragma unroll
      for (int s = 0; s < 2; ++s) {
        #pragma unroll
        for (int r = 0; r < 4; ++r) {
          const unsigned wA = (unsigned)f2bf(SA[2 * s][r]) |
                              ((unsigned)f2bf(SA[2 * s + 1][r]) << 16);
          *(unsigned*)&pbA[(quad * 4 + r) * 40 + n * 2] = wA;
          const unsigned wB = (unsigned)f2bf(SB[2 * s][r]) |
                              ((unsigned)f2bf(SB[2 * s + 1][r]) << 16);
          *(unsigned*)&pbB[(quad * 4 + r) * 40 + n * 2] = wB;
        }
        const int C = cc * 2 + s;
        const s8 apA = *(const s8*)&pbA[n * 40 + quad * 8];
        const s8 apB = *(const s8*)&pbB[n * 40 + quad * 8];
        const s8 bv0 = *(const s8*)&VB[((C * 4 + quad) * 32 + n) * 8];
        const s8 bv1 = *(const s8*)&VB[((C * 4 + quad) * 32 + 16 + n) * 8];
        O0A = __builtin_amdgcn_mfma_f32_16x16x32_bf16(apA, bv0, O0A, 0, 0, 0);
        O1A = __builtin_amdgcn_mfma_f32_16x16x32_bf16(apA, bv1, O1A, 0, 0, 0);
        O0B = __builtin_amdgcn_mfma_f32_16x16x32_bf16(apB, bv0, O0B, 0, 0, 0);
        O1B = __builtin_amdgcn_mfma_f32_16x16x32_bf16(apB, bv1, O1B, 0, 0, 0);
      }
    }

    // ---- finish: sum-reduce over the 16-lane key axis, gate, store ----
    f4 sA = lA, sB = lB;
    #pragma unroll
    for (int sft = 1; sft < 16; sft <<= 1) {
      #pragma unroll
      for (int r = 0; r < 4; ++r) {
        sA[r] += __shfl_xor(sA[r], sft, 64);
        sB[r] += __shfl_xor(sB[r], sft, 64);
      }
    }
    #pragma unroll
    for (int r = 0; r < 4; ++r) {
      const float ivA = 1.0f / sA[r];
      const size_t rowA = (base_i + jrowA + quad * 4 + r) * CZ + h * CH;
      const float gA0 = bf2f(gb[rowA + n]);
      const float gA1 = bf2f(gb[rowA + 16 + n]);
      ogb[rowA + n]      = f2bf(O0A[r] * ivA * gA0);
      ogb[rowA + 16 + n] = f2bf(O1A[r] * ivA * gA1);
      const float ivB = 1.0f / sB[r];
      const size_t rowB = (base_i + jrowB + quad * 4 + r) * CZ + h * CH;
      const float gB0 = bf2f(gb[rowB + n]);
      const float gB1 = bf2f(gb[rowB + 16 + n]);
      ogb[rowB + n]      = f2bf(O0B[r] * ivB * gB0);
      ogb[rowB + 16 + n] = f2bf(O1B[r] * ivB * gB1);
    }
  }
}

// ---------------------------------------------------------------------------
// K3: out = (o*g) @ w_o + b_o.  (unchanged from R10)
//   w_o pre-repacked (wrep+4*16384). LDS = ol only 34816 B.
// ---------------------------------------------------------------------------
template<bool F32>
__global__ __launch_bounds__(256, 2) void k_out(
    const u16* __restrict__ og, const u16* __restrict__ wrep, const void* __restrict__ bo,
    void* __restrict__ outp, const int* __restrict__ flag)
{
  if ((*flag != 0) != F32) return;
  __shared__ __align__(16) u16 ol[128 * 136];
  const u16* WTg = wrep + (size_t)4 * 16384;
  const int t = threadIdx.x;
  const int lane = t & 63;
  const int wid = t >> 6;
  const int n16 = lane & 15;
  const int quad = lane >> 4;
  const int rowBase = blockIdx.x * 128;

  #pragma unroll
  for (int it = 0; it < 8; ++it) {
    const int idx8 = t + it * 256;
    const int r = idx8 >> 4;
    const int c0 = (idx8 & 15) * 8;
    *(us8*)&ol[r * 136 + c0] = *(const us8*)&og[(size_t)(rowBase + r) * CZ + c0];
  }
  __syncthreads();

  f4 acc[2][8];
  #pragma unroll
  for (int i = 0; i < 2; ++i)
    #pragma unroll
    for (int nt = 0; nt < 8; ++nt) acc[i][nt] = f4{0.f, 0.f, 0.f, 0.f};

  #pragma unroll
  for (int ks = 0; ks < 4; ++ks) {
    s8 a[2], b[8];
    #pragma unroll
    for (int i = 0; i < 2; ++i)
      a[i] = *(const s8*)&WTg[ks * 4096 + (((wid * 2 + i) * 4 + quad) * 16 + n16) * 8];
    #pragma unroll
    for (int nt = 0; nt < 8; ++nt)
      b[nt] = *(const s8*)&ol[(nt * 16 + n16) * 136 + ks * 32 + quad * 8];
    #pragma unroll
    for (int i = 0; i < 2; ++i)
      #pragma unroll
      for (int nt = 0; nt < 8; ++nt)
        acc[i][nt] = __builtin_amdgcn_mfma_f32_16x16x32_bf16(a[i], b[nt], acc[i][nt], 0, 0, 0);
  }

  #pragma unroll
  for (int i = 0; i < 2; ++i) {
    const int och0 = (wid * 2 + i) * 16 + quad * 4;
    float b4[4];
    ld4v<F32>(bo, och0, b4);
    #pragma unroll
    for (int nt = 0; nt < 8; ++nt) {
      const size_t off = (size_t)(rowBase + nt * 16 + n16) * CZ + och0;
      if constexpr (F32) {
        float4 o;
        o.x = acc[i][nt][0] + b4[0]; o.y = acc[i][nt][1] + b4[1];
        o.z = acc[i][nt][2] + b4[2]; o.w = acc[i][nt][3] + b4[3];
        *(float4*)&((float*)outp)[off] = o;
      } else {
        us4 o;
        #pragma unroll
        for (int r = 0; r < 4; ++r) o[r] = f2bf(acc[i][nt][r] + b4[r]);
        *(us4*)&((u16*)outp)[off] = o;
      }
    }
  }
}

extern "C" void kernel_launch(void* const* d_in, const int* in_sizes, int n_in,
                              void* d_out, int out_size, void* d_ws, size_t ws_size,
                              hipStream_t stream) {
  const void* z     = d_in[0];
  const void* msk   = d_in[1];
  const void* gma   = d_in[2];
  const void* bta   = d_in[3];
  const void* wbias = d_in[4];
  const void* wq    = d_in[5];
  const void* wk    = d_in[6];
  const void* wv    = d_in[7];
  const void* wg    = d_in[8];
  const void* bg    = d_in[9];
  const void* wo    = d_in[10];
  const void* bo    = d_in[11];

  char* ws = (char*)d_ws;
  int* flag = (int*)ws;
  u16* qb = (u16*)(ws + 256);
  u16* kb = qb + NNCZ;
  u16* vb = kb + NNCZ;
  u16* gb = vb + NNCZ;
  float* triT = (float*)(gb + NNCZ);
  u16* wrep = (u16*)(triT + (size_t)NH * NN);   // 6 * 16384 u16 = 196,608 B
  u16* ogb = qb;  // alias: q slice consumed by the same wave-iteration that writes o

  k_probe<<<dim3(1), dim3(64), 0, stream>>>((const u16*)z, flag);

  k_repack<false><<<dim3(6), dim3(256), 0, stream>>>(wq, wk, wv, wg, wo, wbias, wrep, flag);
  k_repack<true><<<dim3(6), dim3(256), 0, stream>>>(wq, wk, wv, wg, wo, wbias, wrep, flag);

  k_ln_proj<false><<<dim3(NN / 128), dim3(256), 0, stream>>>(
      z, gma, bta, wrep, bg, qb, kb, vb, gb, triT, flag);
  k_ln_proj<true><<<dim3(NN / 128), dim3(256), 0, stream>>>(
      z, gma, bta, wrep, bg, qb, kb, vb, gb, triT, flag);

  k_attn<false><<<dim3(NRES * NH), dim3(256), 0, stream>>>(
      qb, kb, vb, gb, triT, msk, ogb, flag);
  k_attn<true><<<dim3(NRES * NH), dim3(256), 0, stream>>>(
      qb, kb, vb, gb, triT, msk, ogb, flag);

  k_out<false><<<dim3(NN / 128), dim3(256), 0, stream>>>(ogb, wrep, bo, d_out, flag);
  k_out<true><<<dim3(NN / 128), dim3(256), 0, stream>>>(ogb, wrep, bo, d_out, flag);
}